// Round 18
// baseline (1562.471 us; speedup 1.0000x reference)
//
#include <hip/hip_runtime.h>

// ---------------------------------------------------------------------------
// NaViT-ROPE forward. Round 18: fc2 GEMM BK 64->128 (16 MFMA/barrier-pair,
// 12 K-iterations instead of 24; grid-limited so LDS growth is free).
// Rest identical to R17 (1086 us anchor).
// ---------------------------------------------------------------------------

#define EMBED 384
#define NHEADS 6
#define HD 64
#define NSEQ 1024
#define NB 4
#define NROWS (NB * NSEQ)          // 4096
#define PD 96
#define NZ 4                       // split-K factor for attention

typedef __attribute__((ext_vector_type(8))) short bf16x8;
typedef __attribute__((ext_vector_type(4))) float f32x4;

__constant__ int c_lens[4] = {512, 768, 896, 1024};

__device__ __forceinline__ unsigned f2bf(float f) {   // RNE f32->bf16 bits
    unsigned u = __float_as_uint(f);
    return (u + 0x7fffu + ((u >> 16) & 1u)) >> 16;
}
__device__ __forceinline__ float bf2f(unsigned short h) {
    return __uint_as_float(((unsigned)h) << 16);
}

// ---------------------------------------------------------------- patchify (unchanged)
__global__ void patchify_kernel(const float* __restrict__ i0, const float* __restrict__ i1,
                                const float* __restrict__ i2, const float* __restrict__ i3,
                                float* __restrict__ xin, float* __restrict__ cosT,
                                float* __restrict__ sinT) {
    int bn = blockIdx.x;
    int b = bn >> 10, n = bn & 1023;
    const int lens[4] = {512, 768, 896, 1024};
    const int pws[4]  = {128, 192, 224, 256};
    const float* imgs[4] = {i0, i1, i2, i3};
    int len = lens[b], pw = pws[b];
    int W = pw * 4;
    int t = threadIdx.x;               // 128
    float* xrow = xin + (size_t)bn * PD;
    if (n < len) {
        int pr = n / pw, pc = n - pr * pw;
        const float* img = imgs[b];
        if (t < PD) {
            int c = t >> 5, py = (t >> 2) & 7, px = t & 3;
            xrow[t] = img[(size_t)c * 32 * W + (size_t)(pr * 8 + py) * W + pc * 4 + px];
        }
        if (t < 32) {
            int j = t & 15;
            float fr = powf(100.0f, -(float)j / 16.0f);
            float coord = (t < 16) ? (float)pc : (float)pr;
            float ang = coord * fr;
            cosT[(size_t)bn * 32 + t] = cosf(ang);
            sinT[(size_t)bn * 32 + t] = sinf(ang);
        }
    } else {
        if (t < PD) xrow[t] = 0.f;
        if (t < 32) { cosT[(size_t)bn * 32 + t] = 0.f; sinT[(size_t)bn * 32 + t] = 0.f; }
    }
}

// ---------------------------------------------------------------- weight transpose+convert
__global__ void convT_kernel(const float* __restrict__ src, unsigned short* __restrict__ dst,
                             int K, int N, int Kpad) {
    __shared__ float tile[32][33];
    int k0 = blockIdx.x * 32, n0 = blockIdx.y * 32, l = blockIdx.z;
    int t = threadIdx.x;               // 256
    {
        int kk = t >> 3, nn = (t & 7) * 4;
        float4 v = make_float4(0.f, 0.f, 0.f, 0.f);
        if (k0 + kk < K)
            v = *(const float4*)(src + ((size_t)l * K + (k0 + kk)) * N + n0 + nn);
        tile[kk][nn + 0] = v.x; tile[kk][nn + 1] = v.y;
        tile[kk][nn + 2] = v.z; tile[kk][nn + 3] = v.w;
    }
    __syncthreads();
    {
        int nn = t >> 3, kk = (t & 7) * 4;
        unsigned lo = f2bf(tile[kk + 0][nn]) | (f2bf(tile[kk + 1][nn]) << 16);
        unsigned hi = f2bf(tile[kk + 2][nn]) | (f2bf(tile[kk + 3][nn]) << 16);
        uint2 u = make_uint2(lo, hi);
        *(uint2*)(dst + (size_t)l * N * Kpad + (size_t)(n0 + nn) * Kpad + k0 + kk) = u;
    }
}

// ---------------------------------------------------------------- layernorm (wave per row, vectorized)
template <int C, int OS, bool OBF, bool MASK = false>
__global__ void ln_kernel(const float* __restrict__ in, const float* __restrict__ w,
                          const float* __restrict__ bias, void* __restrict__ outv) {
    int row = blockIdx.x * 4 + (threadIdx.x >> 6);
    int t = threadIdx.x & 63;
    const float* x = in + (size_t)row * C;
    constexpr int NS = (C + 127) / 128;
    float2 v[NS];
    float s = 0.f;
#pragma unroll
    for (int i = 0; i < NS; i++) {
        int e = i * 128 + 2 * t;
        v[i] = (e + 1 < C) ? *(const float2*)(x + e) : make_float2(0.f, 0.f);
        s += v[i].x + v[i].y;
    }
#pragma unroll
    for (int off = 32; off; off >>= 1) s += __shfl_down(s, off);
    float mean = __shfl(s, 0) / (float)C;
    float vs = 0.f;
#pragma unroll
    for (int i = 0; i < NS; i++) {
        int e = i * 128 + 2 * t;
        if (e + 1 < C) {
            float d0 = v[i].x - mean, d1 = v[i].y - mean;
            vs += d0 * d0 + d1 * d1;
        }
    }
#pragma unroll
    for (int off = 32; off; off >>= 1) vs += __shfl_down(vs, off);
    float rstd = rsqrtf(__shfl(vs, 0) / (float)C + 1e-5f);
    constexpr int NOS = (OS + 127) / 128;
#pragma unroll
    for (int i = 0; i < NOS; i++) {
        int e = i * 128 + 2 * t;
        float o0 = (e < C)     ? ((v[i].x - mean) * rstd * w[e] + bias[e])         : 0.f;
        float o1 = (e + 1 < C) ? ((v[i].y - mean) * rstd * w[e + 1] + bias[e + 1]) : 0.f;
        if (OBF)
            *(unsigned*)((unsigned short*)outv + (size_t)row * OS + e) =
                f2bf(o0) | (f2bf(o1) << 16);
        else
            *(float2*)((float*)outv + (size_t)row * OS + e) = make_float2(o0, o1);
    }
    if (MASK && t == 0) {
        int b = row >> 10, n = row & 1023;
        ((float*)outv)[(size_t)NROWS * EMBED + row] = (n >= c_lens[b]) ? 1.0f : 0.0f;
    }
}

// ---------------------------------------------------------------- bf16 MFMA GEMM 64x64 tile
// T14 reg-prefetch. FLAGS: 1=bias, 2=gelu, 4=residual(f32), 8=bf16 output
template <int FLAGS>
__global__ __launch_bounds__(256) void gemm_bf16(
    const unsigned short* __restrict__ A, const unsigned short* __restrict__ Wt,
    const float* __restrict__ bias, const float* __restrict__ res,
    float* __restrict__ outf, unsigned short* __restrict__ outb,
    int M, int K, int N) {
    __shared__ unsigned short As[64][72];
    __shared__ unsigned short Bs[64][72];
    int t = threadIdx.x;
    int wid = t >> 6, lane = t & 63;
    int m0 = blockIdx.y * 64, n0 = blockIdx.x * 64;
    int wm = (wid >> 1) * 32, wn = (wid & 1) * 32;
    f32x4 acc[2][2] = {};
    int srow = t >> 2, sc = (t & 3) * 8;
    const unsigned short* Ap = A + (size_t)(m0 + srow) * K + sc;
    const unsigned short* Bp = Wt + (size_t)(n0 + srow) * K + sc;
    int lr = lane & 15, lk = (lane >> 4) * 8;
    uint4 ra0 = *(const uint4*)(Ap);
    uint4 ra1 = *(const uint4*)(Ap + 32);
    uint4 rb0 = *(const uint4*)(Bp);
    uint4 rb1 = *(const uint4*)(Bp + 32);
    for (int k0 = 0; k0 < K; k0 += 64) {
        *(uint4*)&As[srow][sc]      = ra0;
        *(uint4*)&As[srow][sc + 32] = ra1;
        *(uint4*)&Bs[srow][sc]      = rb0;
        *(uint4*)&Bs[srow][sc + 32] = rb1;
        __syncthreads();
        if (k0 + 64 < K) {
            ra0 = *(const uint4*)(Ap + k0 + 64);
            ra1 = *(const uint4*)(Ap + k0 + 96);
            rb0 = *(const uint4*)(Bp + k0 + 64);
            rb1 = *(const uint4*)(Bp + k0 + 96);
        }
#pragma unroll
        for (int kk = 0; kk < 64; kk += 32) {
            bf16x8 a0 = *(const bf16x8*)&As[wm + lr][kk + lk];
            bf16x8 a1 = *(const bf16x8*)&As[wm + 16 + lr][kk + lk];
            bf16x8 b0 = *(const bf16x8*)&Bs[wn + lr][kk + lk];
            bf16x8 b1 = *(const bf16x8*)&Bs[wn + 16 + lr][kk + lk];
            acc[0][0] = __builtin_amdgcn_mfma_f32_16x16x32_bf16(a0, b0, acc[0][0], 0, 0, 0);
            acc[0][1] = __builtin_amdgcn_mfma_f32_16x16x32_bf16(a0, b1, acc[0][1], 0, 0, 0);
            acc[1][0] = __builtin_amdgcn_mfma_f32_16x16x32_bf16(a1, b0, acc[1][0], 0, 0, 0);
            acc[1][1] = __builtin_amdgcn_mfma_f32_16x16x32_bf16(a1, b1, acc[1][1], 0, 0, 0);
        }
        __syncthreads();
    }
    int lq = lane >> 4;
#pragma unroll
    for (int mi = 0; mi < 2; mi++)
#pragma unroll
        for (int ni = 0; ni < 2; ni++) {
#pragma unroll
            for (int r = 0; r < 4; r++) {
                int grow = m0 + wm + mi * 16 + lq * 4 + r;
                int gcol = n0 + wn + ni * 16 + lr;
                float v = acc[mi][ni][r];
                if (FLAGS & 1) v += bias[gcol];
                if (FLAGS & 2) v = 0.5f * v * (1.f + erff(v * 0.70710678118654752f));
                if (FLAGS & 4) v += res[(size_t)grow * N + gcol];
                if (FLAGS & 8) outb[(size_t)grow * N + gcol] = (unsigned short)f2bf(v);
                else           outf[(size_t)grow * N + gcol] = v;
            }
        }
}

// ---------------------------------------------------------------- bf16 MFMA GEMM 64x64, BK=128
// For long-K GEMMs (fc2): 16 MFMA per barrier-pair, half the barriers.
// Grid-limited kernels keep full occupancy despite 34 KB LDS.
template <int FLAGS>
__global__ __launch_bounds__(256) void gemm_bf16_bk128(
    const unsigned short* __restrict__ A, const unsigned short* __restrict__ Wt,
    const float* __restrict__ bias, const float* __restrict__ res,
    float* __restrict__ outf, unsigned short* __restrict__ outb,
    int M, int K, int N) {
    __shared__ unsigned short As[64][136];   // stride 272B: same bank math as [72]
    __shared__ unsigned short Bs[64][136];
    int t = threadIdx.x;
    int wid = t >> 6, lane = t & 63;
    int m0 = blockIdx.y * 64, n0 = blockIdx.x * 64;
    int wm = (wid >> 1) * 32, wn = (wid & 1) * 32;
    f32x4 acc[2][2] = {};
    int srow = t >> 2, sc = (t & 3) * 8;     // sc in {0,8,16,24}; chunks +0,+32,+64,+96
    const unsigned short* Ap = A + (size_t)(m0 + srow) * K + sc;
    const unsigned short* Bp = Wt + (size_t)(n0 + srow) * K + sc;
    int lr = lane & 15, lk = (lane >> 4) * 8;
    uint4 ra[4], rb[4];
#pragma unroll
    for (int j = 0; j < 4; j++) {
        ra[j] = *(const uint4*)(Ap + j * 32);
        rb[j] = *(const uint4*)(Bp + j * 32);
    }
    for (int k0 = 0; k0 < K; k0 += 128) {
#pragma unroll
        for (int j = 0; j < 4; j++) {
            *(uint4*)&As[srow][sc + j * 32] = ra[j];
            *(uint4*)&Bs[srow][sc + j * 32] = rb[j];
        }
        __syncthreads();
        if (k0 + 128 < K) {
#pragma unroll
            for (int j = 0; j < 4; j++) {
                ra[j] = *(const uint4*)(Ap + k0 + 128 + j * 32);
                rb[j] = *(const uint4*)(Bp + k0 + 128 + j * 32);
            }
        }
#pragma unroll
        for (int kk = 0; kk < 128; kk += 32) {
            bf16x8 a0 = *(const bf16x8*)&As[wm + lr][kk + lk];
            bf16x8 a1 = *(const bf16x8*)&As[wm + 16 + lr][kk + lk];
            bf16x8 b0 = *(const bf16x8*)&Bs[wn + lr][kk + lk];
            bf16x8 b1 = *(const bf16x8*)&Bs[wn + 16 + lr][kk + lk];
            acc[0][0] = __builtin_amdgcn_mfma_f32_16x16x32_bf16(a0, b0, acc[0][0], 0, 0, 0);
            acc[0][1] = __builtin_amdgcn_mfma_f32_16x16x32_bf16(a0, b1, acc[0][1], 0, 0, 0);
            acc[1][0] = __builtin_amdgcn_mfma_f32_16x16x32_bf16(a1, b0, acc[1][0], 0, 0, 0);
            acc[1][1] = __builtin_amdgcn_mfma_f32_16x16x32_bf16(a1, b1, acc[1][1], 0, 0, 0);
        }
        __syncthreads();
    }
    int lq = lane >> 4;
#pragma unroll
    for (int mi = 0; mi < 2; mi++)
#pragma unroll
        for (int ni = 0; ni < 2; ni++) {
#pragma unroll
            for (int r = 0; r < 4; r++) {
                int grow = m0 + wm + mi * 16 + lq * 4 + r;
                int gcol = n0 + wn + ni * 16 + lr;
                float v = acc[mi][ni][r];
                if (FLAGS & 1) v += bias[gcol];
                if (FLAGS & 2) v = 0.5f * v * (1.f + erff(v * 0.70710678118654752f));
                if (FLAGS & 4) v += res[(size_t)grow * N + gcol];
                if (FLAGS & 8) outb[(size_t)grow * N + gcol] = (unsigned short)f2bf(v);
                else           outf[(size_t)grow * N + gcol] = v;
            }
        }
}

// ---------------------------------------------------------------- bf16 MFMA GEMM 128x128 tile
template <int FLAGS>
__global__ __launch_bounds__(256) void gemm_bf16_128(
    const unsigned short* __restrict__ A, const unsigned short* __restrict__ Wt,
    const float* __restrict__ bias, const float* __restrict__ res,
    float* __restrict__ outf, unsigned short* __restrict__ outb,
    int M, int K, int N) {
    __shared__ unsigned short As[128][72];
    __shared__ unsigned short Bs[128][72];
    int t = threadIdx.x;
    int wid = t >> 6, lane = t & 63;
    int m0 = blockIdx.y * 128, n0 = blockIdx.x * 128;
    int wm = (wid >> 1) * 64, wn = (wid & 1) * 64;
    f32x4 acc[4][4] = {};
    int srow = t >> 3, sc = (t & 7) * 8;    // rows 0..31, 8-col chunks
    const unsigned short* Ap = A + (size_t)(m0 + srow) * K + sc;
    const unsigned short* Bp = Wt + (size_t)(n0 + srow) * K + sc;
    int lr = lane & 15, lk = (lane >> 4) * 8;
    for (int k0 = 0; k0 < K; k0 += 64) {
#pragma unroll
        for (int rr = 0; rr < 4; rr++) {
            *(uint4*)&As[srow + rr * 32][sc] = *(const uint4*)(Ap + (size_t)(rr * 32) * K + k0);
            *(uint4*)&Bs[srow + rr * 32][sc] = *(const uint4*)(Bp + (size_t)(rr * 32) * K + k0);
        }
        __syncthreads();
#pragma unroll
        for (int kk = 0; kk < 64; kk += 32) {
            bf16x8 af[4], bfr[4];
#pragma unroll
            for (int i = 0; i < 4; i++) af[i]  = *(const bf16x8*)&As[wm + i * 16 + lr][kk + lk];
#pragma unroll
            for (int j = 0; j < 4; j++) bfr[j] = *(const bf16x8*)&Bs[wn + j * 16 + lr][kk + lk];
#pragma unroll
            for (int i = 0; i < 4; i++)
#pragma unroll
                for (int j = 0; j < 4; j++)
                    acc[i][j] = __builtin_amdgcn_mfma_f32_16x16x32_bf16(af[i], bfr[j], acc[i][j], 0, 0, 0);
        }
        __syncthreads();
    }
    int lq = lane >> 4;
#pragma unroll
    for (int mi = 0; mi < 4; mi++)
#pragma unroll
        for (int ni = 0; ni < 4; ni++) {
#pragma unroll
            for (int r = 0; r < 4; r++) {
                int grow = m0 + wm + mi * 16 + lq * 4 + r;
                int gcol = n0 + wn + ni * 16 + lr;
                float v = acc[mi][ni][r];
                if (FLAGS & 1) v += bias[gcol];
                if (FLAGS & 2) v = 0.5f * v * (1.f + erff(v * 0.70710678118654752f));
                if (FLAGS & 4) v += res[(size_t)grow * N + gcol];
                if (FLAGS & 8) outb[(size_t)grow * N + gcol] = (unsigned short)f2bf(v);
                else           outf[(size_t)grow * N + gcol] = v;
            }
        }
}

// ---------------------------------------------------------------- qkv GEMM + fused rope (+prefetch)
__global__ __launch_bounds__(256) void gemm_qkv_rope(
    const unsigned short* __restrict__ A, const unsigned short* __restrict__ Wt,
    const float* __restrict__ bias, const float* __restrict__ cosT,
    const float* __restrict__ sinT, unsigned short* __restrict__ qr,
    unsigned short* __restrict__ kr, unsigned short* __restrict__ vt) {
    const int K = 384;
    __shared__ unsigned short As[64][72];
    __shared__ unsigned short Bs[64][72];
    int t = threadIdx.x;
    int wid = t >> 6, lane = t & 63;
    int m0 = blockIdx.y * 64, n0 = blockIdx.x * 64;
    int wm = (wid >> 1) * 32, wn = (wid & 1) * 32;
    f32x4 acc[2][2] = {};
    int srow = t >> 2, sc = (t & 3) * 8;
    const unsigned short* Ap = A + (size_t)(m0 + srow) * K + sc;
    const unsigned short* Bp = Wt + (size_t)(n0 + srow) * K + sc;
    int lr = lane & 15, lk = (lane >> 4) * 8;
    uint4 ra0 = *(const uint4*)(Ap);
    uint4 ra1 = *(const uint4*)(Ap + 32);
    uint4 rb0 = *(const uint4*)(Bp);
    uint4 rb1 = *(const uint4*)(Bp + 32);
    for (int k0 = 0; k0 < K; k0 += 64) {
        *(uint4*)&As[srow][sc]      = ra0;
        *(uint4*)&As[srow][sc + 32] = ra1;
        *(uint4*)&Bs[srow][sc]      = rb0;
        *(uint4*)&Bs[srow][sc + 32] = rb1;
        __syncthreads();
        if (k0 + 64 < K) {
            ra0 = *(const uint4*)(Ap + k0 + 64);
            ra1 = *(const uint4*)(Ap + k0 + 96);
            rb0 = *(const uint4*)(Bp + k0 + 64);
            rb1 = *(const uint4*)(Bp + k0 + 96);
        }
#pragma unroll
        for (int kk = 0; kk < 64; kk += 32) {
            bf16x8 a0 = *(const bf16x8*)&As[wm + lr][kk + lk];
            bf16x8 a1 = *(const bf16x8*)&As[wm + 16 + lr][kk + lk];
            bf16x8 b0 = *(const bf16x8*)&Bs[wn + lr][kk + lk];
            bf16x8 b1 = *(const bf16x8*)&Bs[wn + 16 + lr][kk + lk];
            acc[0][0] = __builtin_amdgcn_mfma_f32_16x16x32_bf16(a0, b0, acc[0][0], 0, 0, 0);
            acc[0][1] = __builtin_amdgcn_mfma_f32_16x16x32_bf16(a0, b1, acc[0][1], 0, 0, 0);
            acc[1][0] = __builtin_amdgcn_mfma_f32_16x16x32_bf16(a1, b0, acc[1][0], 0, 0, 0);
            acc[1][1] = __builtin_amdgcn_mfma_f32_16x16x32_bf16(a1, b1, acc[1][1], 0, 0, 0);
        }
        __syncthreads();
    }
    int lq = lane >> 4;
    int bx = blockIdx.x;
    int sec = bx / 6, hh = bx - sec * 6;
    if (sec == 2) {
#pragma unroll
        for (int mi = 0; mi < 2; mi++)
#pragma unroll
            for (int ni = 0; ni < 2; ni++) {
                int d = wn + ni * 16 + lr;
                float bb = bias[768 + hh * 64 + d];
                int g0 = m0 + wm + mi * 16 + lq * 4;
                int b = g0 >> 10, n = g0 & 1023;
                uint2 u;
                u.x = f2bf(acc[mi][ni][0] + bb) | (f2bf(acc[mi][ni][1] + bb) << 16);
                u.y = f2bf(acc[mi][ni][2] + bb) | (f2bf(acc[mi][ni][3] + bb) << 16);
                *(uint2*)&vt[((size_t)(b * 6 + hh) * HD + d) * NSEQ + n] = u;
            }
    } else {
        unsigned short* dst = sec ? kr : qr;
        float scl = sec ? 1.0f : 0.125f;
#pragma unroll
        for (int mi = 0; mi < 2; mi++)
#pragma unroll
            for (int ni = 0; ni < 2; ni++) {
                int d = wn + ni * 16 + lr;
                float bb = bias[sec * 384 + hh * 64 + d];
                int pp = d >> 1;
#pragma unroll
                for (int r = 0; r < 4; r++) {
                    int grow = m0 + wm + mi * 16 + lq * 4 + r;
                    float v = acc[mi][ni][r] + bb;
                    float c = cosT[(size_t)grow * 32 + pp];
                    float s = sinT[(size_t)grow * 32 + pp];
                    float vp = __shfl_xor(v, 1);
                    float out = ((d & 1) == 0 ? v * c - vp * s : vp * s + v * c) * scl;
                    int b = grow >> 10, n = grow & 1023;
                    dst[((size_t)(b * 6 + hh) * NSEQ + n) * HD + d] = (unsigned short)f2bf(out);
                }
            }
    }
}

// ---------------------------------------------------------------- split-K(4) attn, Q-tile 128
__global__ __launch_bounds__(256) void attn_mfma(
    const unsigned short* __restrict__ qr, const unsigned short* __restrict__ kr,
    const unsigned short* __restrict__ vt, unsigned short* __restrict__ opart,
    float* __restrict__ mP, float* __restrict__ lP) {
    __shared__ unsigned short Ks[64][72];        // [key][d]
    __shared__ unsigned short Vs[64][72];        // [d][key]
    __shared__ unsigned short Pb[2][4][16][72];  // per-half, per-wave P [q][k]
    __shared__ float Aw[2][4][16];               // per-half alpha/l broadcast
    int bh = blockIdx.x;
    int q0 = blockIdx.y * 128;
    int z  = blockIdx.z;
    int len = c_lens[bh / 6];
    int T = len >> 6;
    int t0 = (T * z) >> 2, t1 = (T * (z + 1)) >> 2;   // NZ=4 quarters
    int t = threadIdx.x, wid = t >> 6, lane = t & 63;
    int lz = lane & 15, lq = lane >> 4;
    bf16x8 qa0[2], qa1[2];
#pragma unroll
    for (int h = 0; h < 2; h++) {
        const unsigned short* Qp =
            qr + ((size_t)bh * NSEQ + q0 + h * 64 + wid * 16 + lz) * HD + lq * 8;
        qa0[h] = *(const bf16x8*)(Qp);
        qa1[h] = *(const bf16x8*)(Qp + 32);
    }
    int srow = t >> 2, sc = (t & 3) * 16;      // K: row=key, V: row=d
    const unsigned short* Kp = kr + (size_t)bh * NSEQ * HD + (size_t)srow * HD + sc;
    const unsigned short* Vp = vt + ((size_t)bh * HD + srow) * NSEQ + sc;
    f32x4 oacc[2][4] = {};
    float m_s[2] = {-1e30f, -1e30f}, l_s[2] = {0.f, 0.f};
    uint4 rk0, rk1, rv0, rv1;
    {
        int k0 = t0 << 6;
        rk0 = *(const uint4*)(Kp + (size_t)k0 * HD);
        rk1 = *(const uint4*)(Kp + (size_t)k0 * HD + 8);
        rv0 = *(const uint4*)(Vp + k0);
        rv1 = *(const uint4*)(Vp + k0 + 8);
    }
    for (int kt = t0; kt < t1; kt++) {
        *(uint4*)&Ks[srow][sc]     = rk0;
        *(uint4*)&Ks[srow][sc + 8] = rk1;
        *(uint4*)&Vs[srow][sc]     = rv0;
        *(uint4*)&Vs[srow][sc + 8] = rv1;
        __syncthreads();
        uint4 nk0, nk1, nv0, nv1;
        if (kt + 1 < t1) {
            int k1 = (kt + 1) << 6;
            nk0 = *(const uint4*)(Kp + (size_t)k1 * HD);
            nk1 = *(const uint4*)(Kp + (size_t)k1 * HD + 8);
            nv0 = *(const uint4*)(Vp + k1);
            nv1 = *(const uint4*)(Vp + k1 + 8);
        }
#pragma unroll
        for (int h = 0; h < 2; h++) {
            f32x4 s[4] = {};
            __builtin_amdgcn_s_setprio(1);
#pragma unroll
            for (int g = 0; g < 4; g++) {
                bf16x8 kf0 = *(const bf16x8*)&Ks[g * 16 + lz][lq * 8];
                bf16x8 kf1 = *(const bf16x8*)&Ks[g * 16 + lz][32 + lq * 8];
                s[g] = __builtin_amdgcn_mfma_f32_16x16x32_bf16(kf0, qa0[h], s[g], 0, 0, 0);
                s[g] = __builtin_amdgcn_mfma_f32_16x16x32_bf16(kf1, qa1[h], s[g], 0, 0, 0);
            }
            __builtin_amdgcn_s_setprio(0);
            float mx = s[0][0];
#pragma unroll
            for (int g = 0; g < 4; g++)
#pragma unroll
                for (int r = 0; r < 4; r++) mx = fmaxf(mx, s[g][r]);
            mx = fmaxf(mx, __shfl_xor(mx, 16));
            mx = fmaxf(mx, __shfl_xor(mx, 32));
            float mn = fmaxf(m_s[h], mx);
            float a_s = __expf(m_s[h] - mn);
            m_s[h] = mn;
            float sum = 0.f;
#pragma unroll
            for (int g = 0; g < 4; g++)
#pragma unroll
                for (int r = 0; r < 4; r++) {
                    float p = __expf(s[g][r] - mn);
                    s[g][r] = p;
                    sum += p;
                }
            sum += __shfl_xor(sum, 16);
            sum += __shfl_xor(sum, 32);
            l_s[h] = l_s[h] * a_s + sum;
            if (lq == 0) Aw[h][wid][lz] = a_s;
#pragma unroll
            for (int g = 0; g < 4; g++) {
                uint2 u;
                u.x = f2bf(s[g][0]) | (f2bf(s[g][1]) << 16);
                u.y = f2bf(s[g][2]) | (f2bf(s[g][3]) << 16);
                *(uint2*)&Pb[h][wid][lz][g * 16 + lq * 4] = u;
            }
            f32x4 al4 = *(const f32x4*)&Aw[h][wid][lq * 4];
            bf16x8 pa0 = *(const bf16x8*)&Pb[h][wid][lz][lq * 8];
            bf16x8 pa1 = *(const bf16x8*)&Pb[h][wid][lz][32 + lq * 8];
            __builtin_amdgcn_s_setprio(1);
#pragma unroll
            for (int g = 0; g < 4; g++) {
#pragma unroll
                for (int r = 0; r < 4; r++) oacc[h][g][r] *= al4[r];
                bf16x8 vf0 = *(const bf16x8*)&Vs[g * 16 + lz][lq * 8];
                bf16x8 vf1 = *(const bf16x8*)&Vs[g * 16 + lz][32 + lq * 8];
                oacc[h][g] = __builtin_amdgcn_mfma_f32_16x16x32_bf16(pa0, vf0, oacc[h][g], 0, 0, 0);
                oacc[h][g] = __builtin_amdgcn_mfma_f32_16x16x32_bf16(pa1, vf1, oacc[h][g], 0, 0, 0);
            }
            __builtin_amdgcn_s_setprio(0);
        }
        __syncthreads();   // all waves done reading before next ds_write
        rk0 = nk0; rk1 = nk1; rv0 = nv0; rv1 = nv1;
    }
#pragma unroll
    for (int h = 0; h < 2; h++) {
        size_t rb = ((size_t)z * 24 + bh) * NSEQ + q0 + h * 64 + wid * 16;
        if (lq == 0) { mP[rb + lz] = m_s[h]; lP[rb + lz] = l_s[h]; }
#pragma unroll
        for (int r = 0; r < 4; r++) {
            int row = lq * 4 + r;
#pragma unroll
            for (int g = 0; g < 4; g++)
                opart[(rb + row) * HD + g * 16 + lz] = (unsigned short)f2bf(oacc[h][g][r]);
        }
    }
}

// ---------------------------------------------------------------- proj GEMM + fused 4-way combine
__global__ __launch_bounds__(256) void gemm_proj_combine(
    const unsigned short* __restrict__ opart, const float* __restrict__ mP,
    const float* __restrict__ lP, const unsigned short* __restrict__ Wt,
    const float* __restrict__ bias, float* __restrict__ xio) {
    const int K = 384, N = 384;
    __shared__ unsigned short As[64][72];
    __shared__ unsigned short Bs[64][72];
    __shared__ float Winv[64][6][NZ];          // 6 KB
    int t = threadIdx.x;
    int wid = t >> 6, lane = t & 63;
    int m0 = blockIdx.y * 64, n0 = blockIdx.x * 64;
    int wm = (wid >> 1) * 32, wn = (wid & 1) * 32;
    const size_t zstride = (size_t)24 * NSEQ * HD;
    for (int p = t; p < 384; p += 256) {
        int tok = p / 6, hh = p - tok * 6;
        int g = m0 + tok, b = g >> 10, n = g & 1023;
        int bh = b * 6 + hh;
        size_t i0 = (size_t)bh * NSEQ + n;
        float m[NZ], l[NZ], w[NZ];
        float ms = -1e30f;
#pragma unroll
        for (int z = 0; z < NZ; z++) {
            m[z] = mP[i0 + (size_t)z * 24 * NSEQ];
            l[z] = lP[i0 + (size_t)z * 24 * NSEQ];
            ms = fmaxf(ms, m[z]);
        }
        float ls = 0.f;
#pragma unroll
        for (int z = 0; z < NZ; z++) { w[z] = __expf(m[z] - ms); ls += l[z] * w[z]; }
        float inv = 1.f / ls;
#pragma unroll
        for (int z = 0; z < NZ; z++) Winv[tok][hh][z] = w[z] * inv;
    }
    __syncthreads();
    f32x4 acc[2][2] = {};
    int srow = t >> 2, sc = (t & 3) * 8;
    int gg = m0 + srow, gb = gg >> 10, gn = gg & 1023;
    const unsigned short* Bp = Wt + (size_t)(n0 + srow) * K + sc;
    int lr = lane & 15, lk = (lane >> 4) * 8;
    for (int k0 = 0; k0 < K; k0 += 64) {
#pragma unroll
        for (int h = 0; h < 2; h++) {
            int col = k0 + sc + h * 32;
            int hh = col >> 6, d = col & 63;
            int bh = gb * 6 + hh;
            size_t base = ((size_t)bh * NSEQ + gn) * HD + d;
            float wz[NZ];
#pragma unroll
            for (int z = 0; z < NZ; z++) wz[z] = Winv[srow][hh][z];
            float lo[4] = {0.f, 0.f, 0.f, 0.f}, hi[4] = {0.f, 0.f, 0.f, 0.f};
#pragma unroll
            for (int z = 0; z < NZ; z++) {
                uint4 u = *(const uint4*)&opart[base + (size_t)z * zstride];
                unsigned a[4] = {u.x, u.y, u.z, u.w};
#pragma unroll
                for (int q = 0; q < 4; q++) {
                    lo[q] += bf2f((unsigned short)(a[q] & 0xffff)) * wz[z];
                    hi[q] += bf2f((unsigned short)(a[q] >> 16)) * wz[z];
                }
            }
            uint4 outw;
            unsigned rr[4];
#pragma unroll
            for (int q = 0; q < 4; q++) rr[q] = f2bf(lo[q]) | (f2bf(hi[q]) << 16);
            outw.x = rr[0]; outw.y = rr[1]; outw.z = rr[2]; outw.w = rr[3];
            *(uint4*)&As[srow][sc + h * 32] = outw;
        }
        *(uint4*)&Bs[srow][sc]      = *(const uint4*)(Bp + k0);
        *(uint4*)&Bs[srow][sc + 32] = *(const uint4*)(Bp + k0 + 32);
        __syncthreads();
#pragma unroll
        for (int kk = 0; kk < 64; kk += 32) {
            bf16x8 a0 = *(const bf16x8*)&As[wm + lr][kk + lk];
            bf16x8 a1 = *(const bf16x8*)&As[wm + 16 + lr][kk + lk];
            bf16x8 b0 = *(const bf16x8*)&Bs[wn + lr][kk + lk];
            bf16x8 b1 = *(const bf16x8*)&Bs[wn + 16 + lr][kk + lk];
            acc[0][0] = __builtin_amdgcn_mfma_f32_16x16x32_bf16(a0, b0, acc[0][0], 0, 0, 0);
            acc[0][1] = __builtin_amdgcn_mfma_f32_16x16x32_bf16(a0, b1, acc[0][1], 0, 0, 0);
            acc[1][0] = __builtin_amdgcn_mfma_f32_16x16x32_bf16(a1, b0, acc[1][0], 0, 0, 0);
            acc[1][1] = __builtin_amdgcn_mfma_f32_16x16x32_bf16(a1, b1, acc[1][1], 0, 0, 0);
        }
        __syncthreads();
    }
    int lq = lane >> 4;
#pragma unroll
    for (int mi = 0; mi < 2; mi++)
#pragma unroll
        for (int ni = 0; ni < 2; ni++) {
#pragma unroll
            for (int r = 0; r < 4; r++) {
                int grow = m0 + wm + mi * 16 + lq * 4 + r;
                int gcol = n0 + wn + ni * 16 + lr;
                float v = acc[mi][ni][r] + bias[gcol] + xio[(size_t)grow * N + gcol];
                xio[(size_t)grow * N + gcol] = v;
            }
        }
}

// ---------------------------------------------------------------- launch
extern "C" void kernel_launch(void* const* d_in, const int* in_sizes, int n_in,
                              void* d_out, int out_size, void* d_ws, size_t ws_size,
                              hipStream_t stream) {
    (void)in_sizes; (void)n_in; (void)out_size; (void)ws_size;
    const float* img0 = (const float*)d_in[0];
    const float* img1 = (const float*)d_in[1];
    const float* img2 = (const float*)d_in[2];
    const float* img3 = (const float*)d_in[3];
    const float* pe_ln_in_w  = (const float*)d_in[4];
    const float* pe_ln_in_b  = (const float*)d_in[5];
    const float* pe_w        = (const float*)d_in[6];
    const float* pe_ln_out_w = (const float*)d_in[7];
    const float* pe_ln_out_b = (const float*)d_in[8];
    const float* ln1_w  = (const float*)d_in[9];
    const float* ln1_b  = (const float*)d_in[10];
    const float* qkv_w  = (const float*)d_in[11];
    const float* qkv_b  = (const float*)d_in[12];
    const float* proj_w = (const float*)d_in[13];
    const float* proj_b = (const float*)d_in[14];
    const float* ln2_w  = (const float*)d_in[15];
    const float* ln2_b  = (const float*)d_in[16];
    const float* fc1_w  = (const float*)d_in[17];
    const float* fc1_b  = (const float*)d_in[18];
    const float* fc2_w  = (const float*)d_in[19];
    const float* fc2_b  = (const float*)d_in[20];
    const float* lnf_w  = (const float*)d_in[21];
    const float* lnf_b  = (const float*)d_in[22];

    char* ws = (char*)d_ws;
    float*          x_f    = (float*)(ws + 0);                    //  6,291,456
    char*           R      = ws + 6291456;                        // 12,582,912 union region
    unsigned short* opart  = (unsigned short*)R;                  // 12,582,912 (attn partials, NZ=4)
    unsigned short* mlp_bf = (unsigned short*)R;                  // 12,582,912 (MLP phase only)
    unsigned short* h_bf   = (unsigned short*)(ws + 18874368);    //  3,145,728 (ln1/ln2 out)
    unsigned short* qr     = (unsigned short*)(ws + 22020096);    //  3,145,728
    unsigned short* kr     = (unsigned short*)(ws + 25165824);    //  3,145,728
    unsigned short* vt     = (unsigned short*)(ws + 28311552);    //  3,145,728
    float*          cosT   = (float*)(ws + 31457280);             //    524,288
    float*          sinT   = (float*)(ws + 31981568);             //    524,288
    float*          xin    = (float*)(ws + 32505856);             //  1,572,864 (dead after embed)
    float*          mPt    = xin;                                 //    393,216 (attn m partials, NZ=4)
    float*          lPt    = (float*)(ws + 32505856 + 393216);    //    393,216 (attn l partials)
    unsigned short* xln_bf = (unsigned short*)(ws + 34078720);    //  1,048,576
    unsigned short* pe_wt  = (unsigned short*)(ws + 35127296);    //     98,304
    unsigned short* qkv_wt = (unsigned short*)(ws + 35225600);    // 10,616,832
    unsigned short* proj_wt= (unsigned short*)(ws + 45842432);    //  3,538,944
    unsigned short* fc1_wt = (unsigned short*)(ws + 49381376);    // 14,155,776
    unsigned short* fc2_wt = (unsigned short*)(ws + 63537152);    // 14,155,776
    // total ~77.7 MB

    convT_kernel<<<dim3(4, 12, 1),   256, 0, stream>>>(pe_w,   pe_wt,   96,  EMBED, 128);
    convT_kernel<<<dim3(12, 36, 12), 256, 0, stream>>>(qkv_w,  qkv_wt,  384, 1152,  384);
    convT_kernel<<<dim3(12, 12, 12), 256, 0, stream>>>(proj_w, proj_wt, 384, 384,   384);
    convT_kernel<<<dim3(12, 48, 12), 256, 0, stream>>>(fc1_w,  fc1_wt,  384, 1536,  384);
    convT_kernel<<<dim3(48, 12, 12), 256, 0, stream>>>(fc2_w,  fc2_wt,  1536, 384,  1536);

    patchify_kernel<<<NROWS, 128, 0, stream>>>(img0, img1, img2, img3, xin, cosT, sinT);
    ln_kernel<PD, 128, true><<<NROWS / 4, 256, 0, stream>>>(xin, pe_ln_in_w, pe_ln_in_b, xln_bf);
    gemm_bf16<0><<<dim3(EMBED / 64, NROWS / 64), 256, 0, stream>>>(
        xln_bf, pe_wt, nullptr, nullptr, x_f, nullptr, NROWS, 128, EMBED);
    ln_kernel<EMBED, EMBED, false><<<NROWS / 4, 256, 0, stream>>>(x_f, pe_ln_out_w, pe_ln_out_b, x_f);

    for (int l = 0; l < 12; ++l) {
        ln_kernel<EMBED, EMBED, true><<<NROWS / 4, 256, 0, stream>>>(
            x_f, ln1_w + l * EMBED, ln1_b + l * EMBED, h_bf);
        gemm_qkv_rope<<<dim3(18, NROWS / 64), 256, 0, stream>>>(
            h_bf, qkv_wt + (size_t)l * 1152 * 384, qkv_b + (size_t)l * 1152,
            cosT, sinT, qr, kr, vt);
        attn_mfma<<<dim3(NB * NHEADS, NSEQ / 128, NZ), 256, 0, stream>>>(
            qr, kr, vt, opart, mPt, lPt);
        gemm_proj_combine<<<dim3(EMBED / 64, NROWS / 64), 256, 0, stream>>>(
            opart, mPt, lPt, proj_wt + (size_t)l * 384 * 384,
            proj_b + (size_t)l * EMBED, x_f);
        ln_kernel<EMBED, EMBED, true><<<NROWS / 4, 256, 0, stream>>>(
            x_f, ln2_w + l * EMBED, ln2_b + l * EMBED, h_bf);
        gemm_bf16_128<11><<<dim3(1536 / 128, NROWS / 128), 256, 0, stream>>>(
            h_bf, fc1_wt + (size_t)l * 1536 * 384, fc1_b + (size_t)l * 1536, nullptr,
            nullptr, mlp_bf, NROWS, EMBED, 1536);
        gemm_bf16_bk128<5><<<dim3(EMBED / 64, NROWS / 64), 256, 0, stream>>>(
            mlp_bf, fc2_wt + (size_t)l * 1536 * 384, fc2_b + (size_t)l * EMBED, x_f,
            x_f, nullptr, NROWS, 1536, EMBED);
    }

    ln_kernel<EMBED, EMBED, false, true><<<NROWS / 4, 256, 0, stream>>>(
        x_f, lnf_w, lnf_b, (float*)d_out);
}

// Round 19
// 1088.948 us; speedup vs baseline: 1.4348x; 1.4348x over previous
//
#include <hip/hip_runtime.h>

// ---------------------------------------------------------------------------
// NaViT-ROPE forward. Round 19: fc2 BK=128 retried with NAMED prefetch
// registers (R18's uint4 arrays spilled to scratch -> 62 MB/dispatch write
// traffic, rule #20). Rest identical to R17 (1086 us anchor).
// ---------------------------------------------------------------------------

#define EMBED 384
#define NHEADS 6
#define HD 64
#define NSEQ 1024
#define NB 4
#define NROWS (NB * NSEQ)          // 4096
#define PD 96
#define NZ 4                       // split-K factor for attention

typedef __attribute__((ext_vector_type(8))) short bf16x8;
typedef __attribute__((ext_vector_type(4))) float f32x4;

__constant__ int c_lens[4] = {512, 768, 896, 1024};

__device__ __forceinline__ unsigned f2bf(float f) {   // RNE f32->bf16 bits
    unsigned u = __float_as_uint(f);
    return (u + 0x7fffu + ((u >> 16) & 1u)) >> 16;
}
__device__ __forceinline__ float bf2f(unsigned short h) {
    return __uint_as_float(((unsigned)h) << 16);
}

// ---------------------------------------------------------------- patchify (unchanged)
__global__ void patchify_kernel(const float* __restrict__ i0, const float* __restrict__ i1,
                                const float* __restrict__ i2, const float* __restrict__ i3,
                                float* __restrict__ xin, float* __restrict__ cosT,
                                float* __restrict__ sinT) {
    int bn = blockIdx.x;
    int b = bn >> 10, n = bn & 1023;
    const int lens[4] = {512, 768, 896, 1024};
    const int pws[4]  = {128, 192, 224, 256};
    const float* imgs[4] = {i0, i1, i2, i3};
    int len = lens[b], pw = pws[b];
    int W = pw * 4;
    int t = threadIdx.x;               // 128
    float* xrow = xin + (size_t)bn * PD;
    if (n < len) {
        int pr = n / pw, pc = n - pr * pw;
        const float* img = imgs[b];
        if (t < PD) {
            int c = t >> 5, py = (t >> 2) & 7, px = t & 3;
            xrow[t] = img[(size_t)c * 32 * W + (size_t)(pr * 8 + py) * W + pc * 4 + px];
        }
        if (t < 32) {
            int j = t & 15;
            float fr = powf(100.0f, -(float)j / 16.0f);
            float coord = (t < 16) ? (float)pc : (float)pr;
            float ang = coord * fr;
            cosT[(size_t)bn * 32 + t] = cosf(ang);
            sinT[(size_t)bn * 32 + t] = sinf(ang);
        }
    } else {
        if (t < PD) xrow[t] = 0.f;
        if (t < 32) { cosT[(size_t)bn * 32 + t] = 0.f; sinT[(size_t)bn * 32 + t] = 0.f; }
    }
}

// ---------------------------------------------------------------- weight transpose+convert
__global__ void convT_kernel(const float* __restrict__ src, unsigned short* __restrict__ dst,
                             int K, int N, int Kpad) {
    __shared__ float tile[32][33];
    int k0 = blockIdx.x * 32, n0 = blockIdx.y * 32, l = blockIdx.z;
    int t = threadIdx.x;               // 256
    {
        int kk = t >> 3, nn = (t & 7) * 4;
        float4 v = make_float4(0.f, 0.f, 0.f, 0.f);
        if (k0 + kk < K)
            v = *(const float4*)(src + ((size_t)l * K + (k0 + kk)) * N + n0 + nn);
        tile[kk][nn + 0] = v.x; tile[kk][nn + 1] = v.y;
        tile[kk][nn + 2] = v.z; tile[kk][nn + 3] = v.w;
    }
    __syncthreads();
    {
        int nn = t >> 3, kk = (t & 7) * 4;
        unsigned lo = f2bf(tile[kk + 0][nn]) | (f2bf(tile[kk + 1][nn]) << 16);
        unsigned hi = f2bf(tile[kk + 2][nn]) | (f2bf(tile[kk + 3][nn]) << 16);
        uint2 u = make_uint2(lo, hi);
        *(uint2*)(dst + (size_t)l * N * Kpad + (size_t)(n0 + nn) * Kpad + k0 + kk) = u;
    }
}

// ---------------------------------------------------------------- layernorm (wave per row, vectorized)
template <int C, int OS, bool OBF, bool MASK = false>
__global__ void ln_kernel(const float* __restrict__ in, const float* __restrict__ w,
                          const float* __restrict__ bias, void* __restrict__ outv) {
    int row = blockIdx.x * 4 + (threadIdx.x >> 6);
    int t = threadIdx.x & 63;
    const float* x = in + (size_t)row * C;
    constexpr int NS = (C + 127) / 128;
    float2 v[NS];
    float s = 0.f;
#pragma unroll
    for (int i = 0; i < NS; i++) {
        int e = i * 128 + 2 * t;
        v[i] = (e + 1 < C) ? *(const float2*)(x + e) : make_float2(0.f, 0.f);
        s += v[i].x + v[i].y;
    }
#pragma unroll
    for (int off = 32; off; off >>= 1) s += __shfl_down(s, off);
    float mean = __shfl(s, 0) / (float)C;
    float vs = 0.f;
#pragma unroll
    for (int i = 0; i < NS; i++) {
        int e = i * 128 + 2 * t;
        if (e + 1 < C) {
            float d0 = v[i].x - mean, d1 = v[i].y - mean;
            vs += d0 * d0 + d1 * d1;
        }
    }
#pragma unroll
    for (int off = 32; off; off >>= 1) vs += __shfl_down(vs, off);
    float rstd = rsqrtf(__shfl(vs, 0) / (float)C + 1e-5f);
    constexpr int NOS = (OS + 127) / 128;
#pragma unroll
    for (int i = 0; i < NOS; i++) {
        int e = i * 128 + 2 * t;
        float o0 = (e < C)     ? ((v[i].x - mean) * rstd * w[e] + bias[e])         : 0.f;
        float o1 = (e + 1 < C) ? ((v[i].y - mean) * rstd * w[e + 1] + bias[e + 1]) : 0.f;
        if (OBF)
            *(unsigned*)((unsigned short*)outv + (size_t)row * OS + e) =
                f2bf(o0) | (f2bf(o1) << 16);
        else
            *(float2*)((float*)outv + (size_t)row * OS + e) = make_float2(o0, o1);
    }
    if (MASK && t == 0) {
        int b = row >> 10, n = row & 1023;
        ((float*)outv)[(size_t)NROWS * EMBED + row] = (n >= c_lens[b]) ? 1.0f : 0.0f;
    }
}

// ---------------------------------------------------------------- bf16 MFMA GEMM 64x64 tile
// T14 reg-prefetch. FLAGS: 1=bias, 2=gelu, 4=residual(f32), 8=bf16 output
template <int FLAGS>
__global__ __launch_bounds__(256) void gemm_bf16(
    const unsigned short* __restrict__ A, const unsigned short* __restrict__ Wt,
    const float* __restrict__ bias, const float* __restrict__ res,
    float* __restrict__ outf, unsigned short* __restrict__ outb,
    int M, int K, int N) {
    __shared__ unsigned short As[64][72];
    __shared__ unsigned short Bs[64][72];
    int t = threadIdx.x;
    int wid = t >> 6, lane = t & 63;
    int m0 = blockIdx.y * 64, n0 = blockIdx.x * 64;
    int wm = (wid >> 1) * 32, wn = (wid & 1) * 32;
    f32x4 acc[2][2] = {};
    int srow = t >> 2, sc = (t & 3) * 8;
    const unsigned short* Ap = A + (size_t)(m0 + srow) * K + sc;
    const unsigned short* Bp = Wt + (size_t)(n0 + srow) * K + sc;
    int lr = lane & 15, lk = (lane >> 4) * 8;
    uint4 ra0 = *(const uint4*)(Ap);
    uint4 ra1 = *(const uint4*)(Ap + 32);
    uint4 rb0 = *(const uint4*)(Bp);
    uint4 rb1 = *(const uint4*)(Bp + 32);
    for (int k0 = 0; k0 < K; k0 += 64) {
        *(uint4*)&As[srow][sc]      = ra0;
        *(uint4*)&As[srow][sc + 32] = ra1;
        *(uint4*)&Bs[srow][sc]      = rb0;
        *(uint4*)&Bs[srow][sc + 32] = rb1;
        __syncthreads();
        if (k0 + 64 < K) {
            ra0 = *(const uint4*)(Ap + k0 + 64);
            ra1 = *(const uint4*)(Ap + k0 + 96);
            rb0 = *(const uint4*)(Bp + k0 + 64);
            rb1 = *(const uint4*)(Bp + k0 + 96);
        }
#pragma unroll
        for (int kk = 0; kk < 64; kk += 32) {
            bf16x8 a0 = *(const bf16x8*)&As[wm + lr][kk + lk];
            bf16x8 a1 = *(const bf16x8*)&As[wm + 16 + lr][kk + lk];
            bf16x8 b0 = *(const bf16x8*)&Bs[wn + lr][kk + lk];
            bf16x8 b1 = *(const bf16x8*)&Bs[wn + 16 + lr][kk + lk];
            acc[0][0] = __builtin_amdgcn_mfma_f32_16x16x32_bf16(a0, b0, acc[0][0], 0, 0, 0);
            acc[0][1] = __builtin_amdgcn_mfma_f32_16x16x32_bf16(a0, b1, acc[0][1], 0, 0, 0);
            acc[1][0] = __builtin_amdgcn_mfma_f32_16x16x32_bf16(a1, b0, acc[1][0], 0, 0, 0);
            acc[1][1] = __builtin_amdgcn_mfma_f32_16x16x32_bf16(a1, b1, acc[1][1], 0, 0, 0);
        }
        __syncthreads();
    }
    int lq = lane >> 4;
#pragma unroll
    for (int mi = 0; mi < 2; mi++)
#pragma unroll
        for (int ni = 0; ni < 2; ni++) {
#pragma unroll
            for (int r = 0; r < 4; r++) {
                int grow = m0 + wm + mi * 16 + lq * 4 + r;
                int gcol = n0 + wn + ni * 16 + lr;
                float v = acc[mi][ni][r];
                if (FLAGS & 1) v += bias[gcol];
                if (FLAGS & 2) v = 0.5f * v * (1.f + erff(v * 0.70710678118654752f));
                if (FLAGS & 4) v += res[(size_t)grow * N + gcol];
                if (FLAGS & 8) outb[(size_t)grow * N + gcol] = (unsigned short)f2bf(v);
                else           outf[(size_t)grow * N + gcol] = v;
            }
        }
}

// ---------------------------------------------------------------- bf16 MFMA GEMM 64x64, BK=128
// Named prefetch registers (no arrays -> no scratch spill). 16 MFMA per
// barrier-pair, 12 K-iterations for K=1536.
template <int FLAGS>
__global__ __launch_bounds__(256) void gemm_bf16_bk128(
    const unsigned short* __restrict__ A, const unsigned short* __restrict__ Wt,
    const float* __restrict__ bias, const float* __restrict__ res,
    float* __restrict__ outf, unsigned short* __restrict__ outb,
    int M, int K, int N) {
    __shared__ unsigned short As[64][136];   // row stride 272B -> 2-way bank alias (free)
    __shared__ unsigned short Bs[64][136];
    int t = threadIdx.x;
    int wid = t >> 6, lane = t & 63;
    int m0 = blockIdx.y * 64, n0 = blockIdx.x * 64;
    int wm = (wid >> 1) * 32, wn = (wid & 1) * 32;
    f32x4 acc[2][2] = {};
    int srow = t >> 2, sc = (t & 3) * 8;     // chunks at sc+0,+32,+64,+96
    const unsigned short* Ap = A + (size_t)(m0 + srow) * K + sc;
    const unsigned short* Bp = Wt + (size_t)(n0 + srow) * K + sc;
    int lr = lane & 15, lk = (lane >> 4) * 8;
    uint4 ra0 = *(const uint4*)(Ap);
    uint4 ra1 = *(const uint4*)(Ap + 32);
    uint4 ra2 = *(const uint4*)(Ap + 64);
    uint4 ra3 = *(const uint4*)(Ap + 96);
    uint4 rb0 = *(const uint4*)(Bp);
    uint4 rb1 = *(const uint4*)(Bp + 32);
    uint4 rb2 = *(const uint4*)(Bp + 64);
    uint4 rb3 = *(const uint4*)(Bp + 96);
    for (int k0 = 0; k0 < K; k0 += 128) {
        *(uint4*)&As[srow][sc]      = ra0;
        *(uint4*)&As[srow][sc + 32] = ra1;
        *(uint4*)&As[srow][sc + 64] = ra2;
        *(uint4*)&As[srow][sc + 96] = ra3;
        *(uint4*)&Bs[srow][sc]      = rb0;
        *(uint4*)&Bs[srow][sc + 32] = rb1;
        *(uint4*)&Bs[srow][sc + 64] = rb2;
        *(uint4*)&Bs[srow][sc + 96] = rb3;
        __syncthreads();
        if (k0 + 128 < K) {
            ra0 = *(const uint4*)(Ap + k0 + 128);
            ra1 = *(const uint4*)(Ap + k0 + 160);
            ra2 = *(const uint4*)(Ap + k0 + 192);
            ra3 = *(const uint4*)(Ap + k0 + 224);
            rb0 = *(const uint4*)(Bp + k0 + 128);
            rb1 = *(const uint4*)(Bp + k0 + 160);
            rb2 = *(const uint4*)(Bp + k0 + 192);
            rb3 = *(const uint4*)(Bp + k0 + 224);
        }
#pragma unroll
        for (int kk = 0; kk < 128; kk += 32) {
            bf16x8 a0 = *(const bf16x8*)&As[wm + lr][kk + lk];
            bf16x8 a1 = *(const bf16x8*)&As[wm + 16 + lr][kk + lk];
            bf16x8 b0 = *(const bf16x8*)&Bs[wn + lr][kk + lk];
            bf16x8 b1 = *(const bf16x8*)&Bs[wn + 16 + lr][kk + lk];
            acc[0][0] = __builtin_amdgcn_mfma_f32_16x16x32_bf16(a0, b0, acc[0][0], 0, 0, 0);
            acc[0][1] = __builtin_amdgcn_mfma_f32_16x16x32_bf16(a0, b1, acc[0][1], 0, 0, 0);
            acc[1][0] = __builtin_amdgcn_mfma_f32_16x16x32_bf16(a1, b0, acc[1][0], 0, 0, 0);
            acc[1][1] = __builtin_amdgcn_mfma_f32_16x16x32_bf16(a1, b1, acc[1][1], 0, 0, 0);
        }
        __syncthreads();
    }
    int lq = lane >> 4;
#pragma unroll
    for (int mi = 0; mi < 2; mi++)
#pragma unroll
        for (int ni = 0; ni < 2; ni++) {
#pragma unroll
            for (int r = 0; r < 4; r++) {
                int grow = m0 + wm + mi * 16 + lq * 4 + r;
                int gcol = n0 + wn + ni * 16 + lr;
                float v = acc[mi][ni][r];
                if (FLAGS & 1) v += bias[gcol];
                if (FLAGS & 2) v = 0.5f * v * (1.f + erff(v * 0.70710678118654752f));
                if (FLAGS & 4) v += res[(size_t)grow * N + gcol];
                if (FLAGS & 8) outb[(size_t)grow * N + gcol] = (unsigned short)f2bf(v);
                else           outf[(size_t)grow * N + gcol] = v;
            }
        }
}

// ---------------------------------------------------------------- bf16 MFMA GEMM 128x128 tile
template <int FLAGS>
__global__ __launch_bounds__(256) void gemm_bf16_128(
    const unsigned short* __restrict__ A, const unsigned short* __restrict__ Wt,
    const float* __restrict__ bias, const float* __restrict__ res,
    float* __restrict__ outf, unsigned short* __restrict__ outb,
    int M, int K, int N) {
    __shared__ unsigned short As[128][72];
    __shared__ unsigned short Bs[128][72];
    int t = threadIdx.x;
    int wid = t >> 6, lane = t & 63;
    int m0 = blockIdx.y * 128, n0 = blockIdx.x * 128;
    int wm = (wid >> 1) * 64, wn = (wid & 1) * 64;
    f32x4 acc[4][4] = {};
    int srow = t >> 3, sc = (t & 7) * 8;    // rows 0..31, 8-col chunks
    const unsigned short* Ap = A + (size_t)(m0 + srow) * K + sc;
    const unsigned short* Bp = Wt + (size_t)(n0 + srow) * K + sc;
    int lr = lane & 15, lk = (lane >> 4) * 8;
    for (int k0 = 0; k0 < K; k0 += 64) {
#pragma unroll
        for (int rr = 0; rr < 4; rr++) {
            *(uint4*)&As[srow + rr * 32][sc] = *(const uint4*)(Ap + (size_t)(rr * 32) * K + k0);
            *(uint4*)&Bs[srow + rr * 32][sc] = *(const uint4*)(Bp + (size_t)(rr * 32) * K + k0);
        }
        __syncthreads();
#pragma unroll
        for (int kk = 0; kk < 64; kk += 32) {
            bf16x8 af[4], bfr[4];
#pragma unroll
            for (int i = 0; i < 4; i++) af[i]  = *(const bf16x8*)&As[wm + i * 16 + lr][kk + lk];
#pragma unroll
            for (int j = 0; j < 4; j++) bfr[j] = *(const bf16x8*)&Bs[wn + j * 16 + lr][kk + lk];
#pragma unroll
            for (int i = 0; i < 4; i++)
#pragma unroll
                for (int j = 0; j < 4; j++)
                    acc[i][j] = __builtin_amdgcn_mfma_f32_16x16x32_bf16(af[i], bfr[j], acc[i][j], 0, 0, 0);
        }
        __syncthreads();
    }
    int lq = lane >> 4;
#pragma unroll
    for (int mi = 0; mi < 4; mi++)
#pragma unroll
        for (int ni = 0; ni < 4; ni++) {
#pragma unroll
            for (int r = 0; r < 4; r++) {
                int grow = m0 + wm + mi * 16 + lq * 4 + r;
                int gcol = n0 + wn + ni * 16 + lr;
                float v = acc[mi][ni][r];
                if (FLAGS & 1) v += bias[gcol];
                if (FLAGS & 2) v = 0.5f * v * (1.f + erff(v * 0.70710678118654752f));
                if (FLAGS & 4) v += res[(size_t)grow * N + gcol];
                if (FLAGS & 8) outb[(size_t)grow * N + gcol] = (unsigned short)f2bf(v);
                else           outf[(size_t)grow * N + gcol] = v;
            }
        }
}

// ---------------------------------------------------------------- qkv GEMM + fused rope (+prefetch)
__global__ __launch_bounds__(256) void gemm_qkv_rope(
    const unsigned short* __restrict__ A, const unsigned short* __restrict__ Wt,
    const float* __restrict__ bias, const float* __restrict__ cosT,
    const float* __restrict__ sinT, unsigned short* __restrict__ qr,
    unsigned short* __restrict__ kr, unsigned short* __restrict__ vt) {
    const int K = 384;
    __shared__ unsigned short As[64][72];
    __shared__ unsigned short Bs[64][72];
    int t = threadIdx.x;
    int wid = t >> 6, lane = t & 63;
    int m0 = blockIdx.y * 64, n0 = blockIdx.x * 64;
    int wm = (wid >> 1) * 32, wn = (wid & 1) * 32;
    f32x4 acc[2][2] = {};
    int srow = t >> 2, sc = (t & 3) * 8;
    const unsigned short* Ap = A + (size_t)(m0 + srow) * K + sc;
    const unsigned short* Bp = Wt + (size_t)(n0 + srow) * K + sc;
    int lr = lane & 15, lk = (lane >> 4) * 8;
    uint4 ra0 = *(const uint4*)(Ap);
    uint4 ra1 = *(const uint4*)(Ap + 32);
    uint4 rb0 = *(const uint4*)(Bp);
    uint4 rb1 = *(const uint4*)(Bp + 32);
    for (int k0 = 0; k0 < K; k0 += 64) {
        *(uint4*)&As[srow][sc]      = ra0;
        *(uint4*)&As[srow][sc + 32] = ra1;
        *(uint4*)&Bs[srow][sc]      = rb0;
        *(uint4*)&Bs[srow][sc + 32] = rb1;
        __syncthreads();
        if (k0 + 64 < K) {
            ra0 = *(const uint4*)(Ap + k0 + 64);
            ra1 = *(const uint4*)(Ap + k0 + 96);
            rb0 = *(const uint4*)(Bp + k0 + 64);
            rb1 = *(const uint4*)(Bp + k0 + 96);
        }
#pragma unroll
        for (int kk = 0; kk < 64; kk += 32) {
            bf16x8 a0 = *(const bf16x8*)&As[wm + lr][kk + lk];
            bf16x8 a1 = *(const bf16x8*)&As[wm + 16 + lr][kk + lk];
            bf16x8 b0 = *(const bf16x8*)&Bs[wn + lr][kk + lk];
            bf16x8 b1 = *(const bf16x8*)&Bs[wn + 16 + lr][kk + lk];
            acc[0][0] = __builtin_amdgcn_mfma_f32_16x16x32_bf16(a0, b0, acc[0][0], 0, 0, 0);
            acc[0][1] = __builtin_amdgcn_mfma_f32_16x16x32_bf16(a0, b1, acc[0][1], 0, 0, 0);
            acc[1][0] = __builtin_amdgcn_mfma_f32_16x16x32_bf16(a1, b0, acc[1][0], 0, 0, 0);
            acc[1][1] = __builtin_amdgcn_mfma_f32_16x16x32_bf16(a1, b1, acc[1][1], 0, 0, 0);
        }
        __syncthreads();
    }
    int lq = lane >> 4;
    int bx = blockIdx.x;
    int sec = bx / 6, hh = bx - sec * 6;
    if (sec == 2) {
#pragma unroll
        for (int mi = 0; mi < 2; mi++)
#pragma unroll
            for (int ni = 0; ni < 2; ni++) {
                int d = wn + ni * 16 + lr;
                float bb = bias[768 + hh * 64 + d];
                int g0 = m0 + wm + mi * 16 + lq * 4;
                int b = g0 >> 10, n = g0 & 1023;
                uint2 u;
                u.x = f2bf(acc[mi][ni][0] + bb) | (f2bf(acc[mi][ni][1] + bb) << 16);
                u.y = f2bf(acc[mi][ni][2] + bb) | (f2bf(acc[mi][ni][3] + bb) << 16);
                *(uint2*)&vt[((size_t)(b * 6 + hh) * HD + d) * NSEQ + n] = u;
            }
    } else {
        unsigned short* dst = sec ? kr : qr;
        float scl = sec ? 1.0f : 0.125f;
#pragma unroll
        for (int mi = 0; mi < 2; mi++)
#pragma unroll
            for (int ni = 0; ni < 2; ni++) {
                int d = wn + ni * 16 + lr;
                float bb = bias[sec * 384 + hh * 64 + d];
                int pp = d >> 1;
#pragma unroll
                for (int r = 0; r < 4; r++) {
                    int grow = m0 + wm + mi * 16 + lq * 4 + r;
                    float v = acc[mi][ni][r] + bb;
                    float c = cosT[(size_t)grow * 32 + pp];
                    float s = sinT[(size_t)grow * 32 + pp];
                    float vp = __shfl_xor(v, 1);
                    float out = ((d & 1) == 0 ? v * c - vp * s : vp * s + v * c) * scl;
                    int b = grow >> 10, n = grow & 1023;
                    dst[((size_t)(b * 6 + hh) * NSEQ + n) * HD + d] = (unsigned short)f2bf(out);
                }
            }
    }
}

// ---------------------------------------------------------------- split-K(4) attn, Q-tile 128
__global__ __launch_bounds__(256) void attn_mfma(
    const unsigned short* __restrict__ qr, const unsigned short* __restrict__ kr,
    const unsigned short* __restrict__ vt, unsigned short* __restrict__ opart,
    float* __restrict__ mP, float* __restrict__ lP) {
    __shared__ unsigned short Ks[64][72];        // [key][d]
    __shared__ unsigned short Vs[64][72];        // [d][key]
    __shared__ unsigned short Pb[2][4][16][72];  // per-half, per-wave P [q][k]
    __shared__ float Aw[2][4][16];               // per-half alpha/l broadcast
    int bh = blockIdx.x;
    int q0 = blockIdx.y * 128;
    int z  = blockIdx.z;
    int len = c_lens[bh / 6];
    int T = len >> 6;
    int t0 = (T * z) >> 2, t1 = (T * (z + 1)) >> 2;   // NZ=4 quarters
    int t = threadIdx.x, wid = t >> 6, lane = t & 63;
    int lz = lane & 15, lq = lane >> 4;
    bf16x8 qa0[2], qa1[2];
#pragma unroll
    for (int h = 0; h < 2; h++) {
        const unsigned short* Qp =
            qr + ((size_t)bh * NSEQ + q0 + h * 64 + wid * 16 + lz) * HD + lq * 8;
        qa0[h] = *(const bf16x8*)(Qp);
        qa1[h] = *(const bf16x8*)(Qp + 32);
    }
    int srow = t >> 2, sc = (t & 3) * 16;      // K: row=key, V: row=d
    const unsigned short* Kp = kr + (size_t)bh * NSEQ * HD + (size_t)srow * HD + sc;
    const unsigned short* Vp = vt + ((size_t)bh * HD + srow) * NSEQ + sc;
    f32x4 oacc[2][4] = {};
    float m_s[2] = {-1e30f, -1e30f}, l_s[2] = {0.f, 0.f};
    uint4 rk0, rk1, rv0, rv1;
    {
        int k0 = t0 << 6;
        rk0 = *(const uint4*)(Kp + (size_t)k0 * HD);
        rk1 = *(const uint4*)(Kp + (size_t)k0 * HD + 8);
        rv0 = *(const uint4*)(Vp + k0);
        rv1 = *(const uint4*)(Vp + k0 + 8);
    }
    for (int kt = t0; kt < t1; kt++) {
        *(uint4*)&Ks[srow][sc]     = rk0;
        *(uint4*)&Ks[srow][sc + 8] = rk1;
        *(uint4*)&Vs[srow][sc]     = rv0;
        *(uint4*)&Vs[srow][sc + 8] = rv1;
        __syncthreads();
        uint4 nk0, nk1, nv0, nv1;
        if (kt + 1 < t1) {
            int k1 = (kt + 1) << 6;
            nk0 = *(const uint4*)(Kp + (size_t)k1 * HD);
            nk1 = *(const uint4*)(Kp + (size_t)k1 * HD + 8);
            nv0 = *(const uint4*)(Vp + k1);
            nv1 = *(const uint4*)(Vp + k1 + 8);
        }
#pragma unroll
        for (int h = 0; h < 2; h++) {
            f32x4 s[4] = {};
            __builtin_amdgcn_s_setprio(1);
#pragma unroll
            for (int g = 0; g < 4; g++) {
                bf16x8 kf0 = *(const bf16x8*)&Ks[g * 16 + lz][lq * 8];
                bf16x8 kf1 = *(const bf16x8*)&Ks[g * 16 + lz][32 + lq * 8];
                s[g] = __builtin_amdgcn_mfma_f32_16x16x32_bf16(kf0, qa0[h], s[g], 0, 0, 0);
                s[g] = __builtin_amdgcn_mfma_f32_16x16x32_bf16(kf1, qa1[h], s[g], 0, 0, 0);
            }
            __builtin_amdgcn_s_setprio(0);
            float mx = s[0][0];
#pragma unroll
            for (int g = 0; g < 4; g++)
#pragma unroll
                for (int r = 0; r < 4; r++) mx = fmaxf(mx, s[g][r]);
            mx = fmaxf(mx, __shfl_xor(mx, 16));
            mx = fmaxf(mx, __shfl_xor(mx, 32));
            float mn = fmaxf(m_s[h], mx);
            float a_s = __expf(m_s[h] - mn);
            m_s[h] = mn;
            float sum = 0.f;
#pragma unroll
            for (int g = 0; g < 4; g++)
#pragma unroll
                for (int r = 0; r < 4; r++) {
                    float p = __expf(s[g][r] - mn);
                    s[g][r] = p;
                    sum += p;
                }
            sum += __shfl_xor(sum, 16);
            sum += __shfl_xor(sum, 32);
            l_s[h] = l_s[h] * a_s + sum;
            if (lq == 0) Aw[h][wid][lz] = a_s;
#pragma unroll
            for (int g = 0; g < 4; g++) {
                uint2 u;
                u.x = f2bf(s[g][0]) | (f2bf(s[g][1]) << 16);
                u.y = f2bf(s[g][2]) | (f2bf(s[g][3]) << 16);
                *(uint2*)&Pb[h][wid][lz][g * 16 + lq * 4] = u;
            }
            f32x4 al4 = *(const f32x4*)&Aw[h][wid][lq * 4];
            bf16x8 pa0 = *(const bf16x8*)&Pb[h][wid][lz][lq * 8];
            bf16x8 pa1 = *(const bf16x8*)&Pb[h][wid][lz][32 + lq * 8];
            __builtin_amdgcn_s_setprio(1);
#pragma unroll
            for (int g = 0; g < 4; g++) {
#pragma unroll
                for (int r = 0; r < 4; r++) oacc[h][g][r] *= al4[r];
                bf16x8 vf0 = *(const bf16x8*)&Vs[g * 16 + lz][lq * 8];
                bf16x8 vf1 = *(const bf16x8*)&Vs[g * 16 + lz][32 + lq * 8];
                oacc[h][g] = __builtin_amdgcn_mfma_f32_16x16x32_bf16(pa0, vf0, oacc[h][g], 0, 0, 0);
                oacc[h][g] = __builtin_amdgcn_mfma_f32_16x16x32_bf16(pa1, vf1, oacc[h][g], 0, 0, 0);
            }
            __builtin_amdgcn_s_setprio(0);
        }
        __syncthreads();   // all waves done reading before next ds_write
        rk0 = nk0; rk1 = nk1; rv0 = nv0; rv1 = nv1;
    }
#pragma unroll
    for (int h = 0; h < 2; h++) {
        size_t rb = ((size_t)z * 24 + bh) * NSEQ + q0 + h * 64 + wid * 16;
        if (lq == 0) { mP[rb + lz] = m_s[h]; lP[rb + lz] = l_s[h]; }
#pragma unroll
        for (int r = 0; r < 4; r++) {
            int row = lq * 4 + r;
#pragma unroll
            for (int g = 0; g < 4; g++)
                opart[(rb + row) * HD + g * 16 + lz] = (unsigned short)f2bf(oacc[h][g][r]);
        }
    }
}

// ---------------------------------------------------------------- proj GEMM + fused 4-way combine
__global__ __launch_bounds__(256) void gemm_proj_combine(
    const unsigned short* __restrict__ opart, const float* __restrict__ mP,
    const float* __restrict__ lP, const unsigned short* __restrict__ Wt,
    const float* __restrict__ bias, float* __restrict__ xio) {
    const int K = 384, N = 384;
    __shared__ unsigned short As[64][72];
    __shared__ unsigned short Bs[64][72];
    __shared__ float Winv[64][6][NZ];          // 6 KB
    int t = threadIdx.x;
    int wid = t >> 6, lane = t & 63;
    int m0 = blockIdx.y * 64, n0 = blockIdx.x * 64;
    int wm = (wid >> 1) * 32, wn = (wid & 1) * 32;
    const size_t zstride = (size_t)24 * NSEQ * HD;
    for (int p = t; p < 384; p += 256) {
        int tok = p / 6, hh = p - tok * 6;
        int g = m0 + tok, b = g >> 10, n = g & 1023;
        int bh = b * 6 + hh;
        size_t i0 = (size_t)bh * NSEQ + n;
        float m[NZ], l[NZ], w[NZ];
        float ms = -1e30f;
#pragma unroll
        for (int z = 0; z < NZ; z++) {
            m[z] = mP[i0 + (size_t)z * 24 * NSEQ];
            l[z] = lP[i0 + (size_t)z * 24 * NSEQ];
            ms = fmaxf(ms, m[z]);
        }
        float ls = 0.f;
#pragma unroll
        for (int z = 0; z < NZ; z++) { w[z] = __expf(m[z] - ms); ls += l[z] * w[z]; }
        float inv = 1.f / ls;
#pragma unroll
        for (int z = 0; z < NZ; z++) Winv[tok][hh][z] = w[z] * inv;
    }
    __syncthreads();
    f32x4 acc[2][2] = {};
    int srow = t >> 2, sc = (t & 3) * 8;
    int gg = m0 + srow, gb = gg >> 10, gn = gg & 1023;
    const unsigned short* Bp = Wt + (size_t)(n0 + srow) * K + sc;
    int lr = lane & 15, lk = (lane >> 4) * 8;
    for (int k0 = 0; k0 < K; k0 += 64) {
#pragma unroll
        for (int h = 0; h < 2; h++) {
            int col = k0 + sc + h * 32;
            int hh = col >> 6, d = col & 63;
            int bh = gb * 6 + hh;
            size_t base = ((size_t)bh * NSEQ + gn) * HD + d;
            float wz[NZ];
#pragma unroll
            for (int z = 0; z < NZ; z++) wz[z] = Winv[srow][hh][z];
            float lo[4] = {0.f, 0.f, 0.f, 0.f}, hi[4] = {0.f, 0.f, 0.f, 0.f};
#pragma unroll
            for (int z = 0; z < NZ; z++) {
                uint4 u = *(const uint4*)&opart[base + (size_t)z * zstride];
                unsigned a[4] = {u.x, u.y, u.z, u.w};
#pragma unroll
                for (int q = 0; q < 4; q++) {
                    lo[q] += bf2f((unsigned short)(a[q] & 0xffff)) * wz[z];
                    hi[q] += bf2f((unsigned short)(a[q] >> 16)) * wz[z];
                }
            }
            uint4 outw;
            unsigned rr[4];
#pragma unroll
            for (int q = 0; q < 4; q++) rr[q] = f2bf(lo[q]) | (f2bf(hi[q]) << 16);
            outw.x = rr[0]; outw.y = rr[1]; outw.z = rr[2]; outw.w = rr[3];
            *(uint4*)&As[srow][sc + h * 32] = outw;
        }
        *(uint4*)&Bs[srow][sc]      = *(const uint4*)(Bp + k0);
        *(uint4*)&Bs[srow][sc + 32] = *(const uint4*)(Bp + k0 + 32);
        __syncthreads();
#pragma unroll
        for (int kk = 0; kk < 64; kk += 32) {
            bf16x8 a0 = *(const bf16x8*)&As[wm + lr][kk + lk];
            bf16x8 a1 = *(const bf16x8*)&As[wm + 16 + lr][kk + lk];
            bf16x8 b0 = *(const bf16x8*)&Bs[wn + lr][kk + lk];
            bf16x8 b1 = *(const bf16x8*)&Bs[wn + 16 + lr][kk + lk];
            acc[0][0] = __builtin_amdgcn_mfma_f32_16x16x32_bf16(a0, b0, acc[0][0], 0, 0, 0);
            acc[0][1] = __builtin_amdgcn_mfma_f32_16x16x32_bf16(a0, b1, acc[0][1], 0, 0, 0);
            acc[1][0] = __builtin_amdgcn_mfma_f32_16x16x32_bf16(a1, b0, acc[1][0], 0, 0, 0);
            acc[1][1] = __builtin_amdgcn_mfma_f32_16x16x32_bf16(a1, b1, acc[1][1], 0, 0, 0);
        }
        __syncthreads();
    }
    int lq = lane >> 4;
#pragma unroll
    for (int mi = 0; mi < 2; mi++)
#pragma unroll
        for (int ni = 0; ni < 2; ni++) {
#pragma unroll
            for (int r = 0; r < 4; r++) {
                int grow = m0 + wm + mi * 16 + lq * 4 + r;
                int gcol = n0 + wn + ni * 16 + lr;
                float v = acc[mi][ni][r] + bias[gcol] + xio[(size_t)grow * N + gcol];
                xio[(size_t)grow * N + gcol] = v;
            }
        }
}

// ---------------------------------------------------------------- launch
extern "C" void kernel_launch(void* const* d_in, const int* in_sizes, int n_in,
                              void* d_out, int out_size, void* d_ws, size_t ws_size,
                              hipStream_t stream) {
    (void)in_sizes; (void)n_in; (void)out_size; (void)ws_size;
    const float* img0 = (const float*)d_in[0];
    const float* img1 = (const float*)d_in[1];
    const float* img2 = (const float*)d_in[2];
    const float* img3 = (const float*)d_in[3];
    const float* pe_ln_in_w  = (const float*)d_in[4];
    const float* pe_ln_in_b  = (const float*)d_in[5];
    const float* pe_w        = (const float*)d_in[6];
    const float* pe_ln_out_w = (const float*)d_in[7];
    const float* pe_ln_out_b = (const float*)d_in[8];
    const float* ln1_w  = (const float*)d_in[9];
    const float* ln1_b  = (const float*)d_in[10];
    const float* qkv_w  = (const float*)d_in[11];
    const float* qkv_b  = (const float*)d_in[12];
    const float* proj_w = (const float*)d_in[13];
    const float* proj_b = (const float*)d_in[14];
    const float* ln2_w  = (const float*)d_in[15];
    const float* ln2_b  = (const float*)d_in[16];
    const float* fc1_w  = (const float*)d_in[17];
    const float* fc1_b  = (const float*)d_in[18];
    const float* fc2_w  = (const float*)d_in[19];
    const float* fc2_b  = (const float*)d_in[20];
    const float* lnf_w  = (const float*)d_in[21];
    const float* lnf_b  = (const float*)d_in[22];

    char* ws = (char*)d_ws;
    float*          x_f    = (float*)(ws + 0);                    //  6,291,456
    char*           R      = ws + 6291456;                        // 12,582,912 union region
    unsigned short* opart  = (unsigned short*)R;                  // 12,582,912 (attn partials, NZ=4)
    unsigned short* mlp_bf = (unsigned short*)R;                  // 12,582,912 (MLP phase only)
    unsigned short* h_bf   = (unsigned short*)(ws + 18874368);    //  3,145,728 (ln1/ln2 out)
    unsigned short* qr     = (unsigned short*)(ws + 22020096);    //  3,145,728
    unsigned short* kr     = (unsigned short*)(ws + 25165824);    //  3,145,728
    unsigned short* vt     = (unsigned short*)(ws + 28311552);    //  3,145,728
    float*          cosT   = (float*)(ws + 31457280);             //    524,288
    float*          sinT   = (float*)(ws + 31981568);             //    524,288
    float*          xin    = (float*)(ws + 32505856);             //  1,572,864 (dead after embed)
    float*          mPt    = xin;                                 //    393,216 (attn m partials, NZ=4)
    float*          lPt    = (float*)(ws + 32505856 + 393216);    //    393,216 (attn l partials)
    unsigned short* xln_bf = (unsigned short*)(ws + 34078720);    //  1,048,576
    unsigned short* pe_wt  = (unsigned short*)(ws + 35127296);    //     98,304
    unsigned short* qkv_wt = (unsigned short*)(ws + 35225600);    // 10,616,832
    unsigned short* proj_wt= (unsigned short*)(ws + 45842432);    //  3,538,944
    unsigned short* fc1_wt = (unsigned short*)(ws + 49381376);    // 14,155,776
    unsigned short* fc2_wt = (unsigned short*)(ws + 63537152);    // 14,155,776
    // total ~77.7 MB

    convT_kernel<<<dim3(4, 12, 1),   256, 0, stream>>>(pe_w,   pe_wt,   96,  EMBED, 128);
    convT_kernel<<<dim3(12, 36, 12), 256, 0, stream>>>(qkv_w,  qkv_wt,  384, 1152,  384);
    convT_kernel<<<dim3(12, 12, 12), 256, 0, stream>>>(proj_w, proj_wt, 384, 384,   384);
    convT_kernel<<<dim3(12, 48, 12), 256, 0, stream>>>(fc1_w,  fc1_wt,  384, 1536,  384);
    convT_kernel<<<dim3(48, 12, 12), 256, 0, stream>>>(fc2_w,  fc2_wt,  1536, 384,  1536);

    patchify_kernel<<<NROWS, 128, 0, stream>>>(img0, img1, img2, img3, xin, cosT, sinT);
    ln_kernel<PD, 128, true><<<NROWS / 4, 256, 0, stream>>>(xin, pe_ln_in_w, pe_ln_in_b, xln_bf);
    gemm_bf16<0><<<dim3(EMBED / 64, NROWS / 64), 256, 0, stream>>>(
        xln_bf, pe_wt, nullptr, nullptr, x_f, nullptr, NROWS, 128, EMBED);
    ln_kernel<EMBED, EMBED, false><<<NROWS / 4, 256, 0, stream>>>(x_f, pe_ln_out_w, pe_ln_out_b, x_f);

    for (int l = 0; l < 12; ++l) {
        ln_kernel<EMBED, EMBED, true><<<NROWS / 4, 256, 0, stream>>>(
            x_f, ln1_w + l * EMBED, ln1_b + l * EMBED, h_bf);
        gemm_qkv_rope<<<dim3(18, NROWS / 64), 256, 0, stream>>>(
            h_bf, qkv_wt + (size_t)l * 1152 * 384, qkv_b + (size_t)l * 1152,
            cosT, sinT, qr, kr, vt);
        attn_mfma<<<dim3(NB * NHEADS, NSEQ / 128, NZ), 256, 0, stream>>>(
            qr, kr, vt, opart, mPt, lPt);
        gemm_proj_combine<<<dim3(EMBED / 64, NROWS / 64), 256, 0, stream>>>(
            opart, mPt, lPt, proj_wt + (size_t)l * 384 * 384,
            proj_b + (size_t)l * EMBED, x_f);
        ln_kernel<EMBED, EMBED, true><<<NROWS / 4, 256, 0, stream>>>(
            x_f, ln2_w + l * EMBED, ln2_b + l * EMBED, h_bf);
        gemm_bf16_128<11><<<dim3(1536 / 128, NROWS / 128), 256, 0, stream>>>(
            h_bf, fc1_wt + (size_t)l * 1536 * 384, fc1_b + (size_t)l * 1536, nullptr,
            nullptr, mlp_bf, NROWS, EMBED, 1536);
        gemm_bf16_bk128<5><<<dim3(EMBED / 64, NROWS / 64), 256, 0, stream>>>(
            mlp_bf, fc2_wt + (size_t)l * 1536 * 384, fc2_b + (size_t)l * EMBED, x_f,
            x_f, nullptr, NROWS, 1536, EMBED);
    }

    ln_kernel<EMBED, EMBED, false, true><<<NROWS / 4, 256, 0, stream>>>(
        x_f, lnf_w, lnf_b, (float*)d_out);
}

// Round 20
// 1074.533 us; speedup vs baseline: 1.4541x; 1.0134x over previous
//
#include <hip/hip_runtime.h>

// ---------------------------------------------------------------------------
// NaViT-ROPE forward. Round 20: prologue consolidated — 5 convT dispatches +
// patchify merged into ONE flattened dispatch (independent work; removes 5
// stream-serialization boundaries). Rest identical to R19 (1086-89 plateau).
// ---------------------------------------------------------------------------

#define EMBED 384
#define NHEADS 6
#define HD 64
#define NSEQ 1024
#define NB 4
#define NROWS (NB * NSEQ)          // 4096
#define PD 96
#define NZ 4                       // split-K factor for attention

typedef __attribute__((ext_vector_type(8))) short bf16x8;
typedef __attribute__((ext_vector_type(4))) float f32x4;

__constant__ int c_lens[4] = {512, 768, 896, 1024};

__device__ __forceinline__ unsigned f2bf(float f) {   // RNE f32->bf16 bits
    unsigned u = __float_as_uint(f);
    return (u + 0x7fffu + ((u >> 16) & 1u)) >> 16;
}
__device__ __forceinline__ float bf2f(unsigned short h) {
    return __uint_as_float(((unsigned)h) << 16);
}

// ---------------------------------------------------------------- fused prologue
// One dispatch: patchify (blocks 0..4095) + 5 weight transpose+convert jobs
// (flattened). 256 threads/block for all jobs.
__global__ __launch_bounds__(256) void prologue_kernel(
    const float* __restrict__ i0, const float* __restrict__ i1,
    const float* __restrict__ i2, const float* __restrict__ i3,
    float* __restrict__ xin, float* __restrict__ cosT, float* __restrict__ sinT,
    const float* __restrict__ pe_w,   unsigned short* __restrict__ pe_wt,
    const float* __restrict__ qkv_w,  unsigned short* __restrict__ qkv_wt,
    const float* __restrict__ proj_w, unsigned short* __restrict__ proj_wt,
    const float* __restrict__ fc1_w,  unsigned short* __restrict__ fc1_wt,
    const float* __restrict__ fc2_w,  unsigned short* __restrict__ fc2_wt) {
    __shared__ float tile[32][33];
    int id = blockIdx.x;
    int t = threadIdx.x;
    if (id < 4096) {
        // ---- patchify (body identical to R19's patchify_kernel) ----
        int bn = id;
        int b = bn >> 10, n = bn & 1023;
        const int lens[4] = {512, 768, 896, 1024};
        const int pws[4]  = {128, 192, 224, 256};
        const float* imgs[4] = {i0, i1, i2, i3};
        int len = lens[b], pw = pws[b];
        int W = pw * 4;
        float* xrow = xin + (size_t)bn * PD;
        if (n < len) {
            int pr = n / pw, pc = n - pr * pw;
            const float* img = imgs[b];
            if (t < PD) {
                int c = t >> 5, py = (t >> 2) & 7, px = t & 3;
                xrow[t] = img[(size_t)c * 32 * W + (size_t)(pr * 8 + py) * W + pc * 4 + px];
            }
            if (t < 32) {
                int j = t & 15;
                float fr = powf(100.0f, -(float)j / 16.0f);
                float coord = (t < 16) ? (float)pc : (float)pr;
                float ang = coord * fr;
                cosT[(size_t)bn * 32 + t] = cosf(ang);
                sinT[(size_t)bn * 32 + t] = sinf(ang);
            }
        } else {
            if (t < PD) xrow[t] = 0.f;
            if (t < 32) { cosT[(size_t)bn * 32 + t] = 0.f; sinT[(size_t)bn * 32 + t] = 0.f; }
        }
        return;
    }
    // ---- convT jobs, flattened ----
    int r = id - 4096;
    const float* src; unsigned short* dst; int K, N, Kpad, KX, KY;
    if (r < 48)        { src = pe_w;   dst = pe_wt;   K = 96;   N = 384;  Kpad = 128;  KX = 4;  KY = 12; }
    else if ((r -= 48) < 5184)   { src = qkv_w;  dst = qkv_wt;  K = 384;  N = 1152; Kpad = 384;  KX = 12; KY = 36; }
    else if ((r -= 5184) < 1728) { src = proj_w; dst = proj_wt; K = 384;  N = 384;  Kpad = 384;  KX = 12; KY = 12; }
    else if ((r -= 1728) < 6912) { src = fc1_w;  dst = fc1_wt;  K = 384;  N = 1536; Kpad = 384;  KX = 12; KY = 48; }
    else { r -= 6912;    src = fc2_w;  dst = fc2_wt;  K = 1536; N = 384;  Kpad = 1536; KX = 48; KY = 12; }
    int k0 = (r % KX) * 32;
    int rest = r / KX;
    int n0 = (rest % KY) * 32;
    int l = rest / KY;
    {
        int kk = t >> 3, nn = (t & 7) * 4;
        float4 v = make_float4(0.f, 0.f, 0.f, 0.f);
        if (k0 + kk < K)
            v = *(const float4*)(src + ((size_t)l * K + (k0 + kk)) * N + n0 + nn);
        tile[kk][nn + 0] = v.x; tile[kk][nn + 1] = v.y;
        tile[kk][nn + 2] = v.z; tile[kk][nn + 3] = v.w;
    }
    __syncthreads();
    {
        int nn = t >> 3, kk = (t & 7) * 4;
        unsigned lo = f2bf(tile[kk + 0][nn]) | (f2bf(tile[kk + 1][nn]) << 16);
        unsigned hi = f2bf(tile[kk + 2][nn]) | (f2bf(tile[kk + 3][nn]) << 16);
        uint2 u = make_uint2(lo, hi);
        *(uint2*)(dst + (size_t)l * N * Kpad + (size_t)(n0 + nn) * Kpad + k0 + kk) = u;
    }
}

// ---------------------------------------------------------------- layernorm (wave per row, vectorized)
template <int C, int OS, bool OBF, bool MASK = false>
__global__ void ln_kernel(const float* __restrict__ in, const float* __restrict__ w,
                          const float* __restrict__ bias, void* __restrict__ outv) {
    int row = blockIdx.x * 4 + (threadIdx.x >> 6);
    int t = threadIdx.x & 63;
    const float* x = in + (size_t)row * C;
    constexpr int NS = (C + 127) / 128;
    float2 v[NS];
    float s = 0.f;
#pragma unroll
    for (int i = 0; i < NS; i++) {
        int e = i * 128 + 2 * t;
        v[i] = (e + 1 < C) ? *(const float2*)(x + e) : make_float2(0.f, 0.f);
        s += v[i].x + v[i].y;
    }
#pragma unroll
    for (int off = 32; off; off >>= 1) s += __shfl_down(s, off);
    float mean = __shfl(s, 0) / (float)C;
    float vs = 0.f;
#pragma unroll
    for (int i = 0; i < NS; i++) {
        int e = i * 128 + 2 * t;
        if (e + 1 < C) {
            float d0 = v[i].x - mean, d1 = v[i].y - mean;
            vs += d0 * d0 + d1 * d1;
        }
    }
#pragma unroll
    for (int off = 32; off; off >>= 1) vs += __shfl_down(vs, off);
    float rstd = rsqrtf(__shfl(vs, 0) / (float)C + 1e-5f);
    constexpr int NOS = (OS + 127) / 128;
#pragma unroll
    for (int i = 0; i < NOS; i++) {
        int e = i * 128 + 2 * t;
        float o0 = (e < C)     ? ((v[i].x - mean) * rstd * w[e] + bias[e])         : 0.f;
        float o1 = (e + 1 < C) ? ((v[i].y - mean) * rstd * w[e + 1] + bias[e + 1]) : 0.f;
        if (OBF)
            *(unsigned*)((unsigned short*)outv + (size_t)row * OS + e) =
                f2bf(o0) | (f2bf(o1) << 16);
        else
            *(float2*)((float*)outv + (size_t)row * OS + e) = make_float2(o0, o1);
    }
    if (MASK && t == 0) {
        int b = row >> 10, n = row & 1023;
        ((float*)outv)[(size_t)NROWS * EMBED + row] = (n >= c_lens[b]) ? 1.0f : 0.0f;
    }
}

// ---------------------------------------------------------------- bf16 MFMA GEMM 64x64 tile
// T14 reg-prefetch. FLAGS: 1=bias, 2=gelu, 4=residual(f32), 8=bf16 output
template <int FLAGS>
__global__ __launch_bounds__(256) void gemm_bf16(
    const unsigned short* __restrict__ A, const unsigned short* __restrict__ Wt,
    const float* __restrict__ bias, const float* __restrict__ res,
    float* __restrict__ outf, unsigned short* __restrict__ outb,
    int M, int K, int N) {
    __shared__ unsigned short As[64][72];
    __shared__ unsigned short Bs[64][72];
    int t = threadIdx.x;
    int wid = t >> 6, lane = t & 63;
    int m0 = blockIdx.y * 64, n0 = blockIdx.x * 64;
    int wm = (wid >> 1) * 32, wn = (wid & 1) * 32;
    f32x4 acc[2][2] = {};
    int srow = t >> 2, sc = (t & 3) * 8;
    const unsigned short* Ap = A + (size_t)(m0 + srow) * K + sc;
    const unsigned short* Bp = Wt + (size_t)(n0 + srow) * K + sc;
    int lr = lane & 15, lk = (lane >> 4) * 8;
    uint4 ra0 = *(const uint4*)(Ap);
    uint4 ra1 = *(const uint4*)(Ap + 32);
    uint4 rb0 = *(const uint4*)(Bp);
    uint4 rb1 = *(const uint4*)(Bp + 32);
    for (int k0 = 0; k0 < K; k0 += 64) {
        *(uint4*)&As[srow][sc]      = ra0;
        *(uint4*)&As[srow][sc + 32] = ra1;
        *(uint4*)&Bs[srow][sc]      = rb0;
        *(uint4*)&Bs[srow][sc + 32] = rb1;
        __syncthreads();
        if (k0 + 64 < K) {
            ra0 = *(const uint4*)(Ap + k0 + 64);
            ra1 = *(const uint4*)(Ap + k0 + 96);
            rb0 = *(const uint4*)(Bp + k0 + 64);
            rb1 = *(const uint4*)(Bp + k0 + 96);
        }
#pragma unroll
        for (int kk = 0; kk < 64; kk += 32) {
            bf16x8 a0 = *(const bf16x8*)&As[wm + lr][kk + lk];
            bf16x8 a1 = *(const bf16x8*)&As[wm + 16 + lr][kk + lk];
            bf16x8 b0 = *(const bf16x8*)&Bs[wn + lr][kk + lk];
            bf16x8 b1 = *(const bf16x8*)&Bs[wn + 16 + lr][kk + lk];
            acc[0][0] = __builtin_amdgcn_mfma_f32_16x16x32_bf16(a0, b0, acc[0][0], 0, 0, 0);
            acc[0][1] = __builtin_amdgcn_mfma_f32_16x16x32_bf16(a0, b1, acc[0][1], 0, 0, 0);
            acc[1][0] = __builtin_amdgcn_mfma_f32_16x16x32_bf16(a1, b0, acc[1][0], 0, 0, 0);
            acc[1][1] = __builtin_amdgcn_mfma_f32_16x16x32_bf16(a1, b1, acc[1][1], 0, 0, 0);
        }
        __syncthreads();
    }
    int lq = lane >> 4;
#pragma unroll
    for (int mi = 0; mi < 2; mi++)
#pragma unroll
        for (int ni = 0; ni < 2; ni++) {
#pragma unroll
            for (int r = 0; r < 4; r++) {
                int grow = m0 + wm + mi * 16 + lq * 4 + r;
                int gcol = n0 + wn + ni * 16 + lr;
                float v = acc[mi][ni][r];
                if (FLAGS & 1) v += bias[gcol];
                if (FLAGS & 2) v = 0.5f * v * (1.f + erff(v * 0.70710678118654752f));
                if (FLAGS & 4) v += res[(size_t)grow * N + gcol];
                if (FLAGS & 8) outb[(size_t)grow * N + gcol] = (unsigned short)f2bf(v);
                else           outf[(size_t)grow * N + gcol] = v;
            }
        }
}

// ---------------------------------------------------------------- bf16 MFMA GEMM 64x64, BK=128
// Named prefetch registers (no arrays -> no scratch spill).
template <int FLAGS>
__global__ __launch_bounds__(256) void gemm_bf16_bk128(
    const unsigned short* __restrict__ A, const unsigned short* __restrict__ Wt,
    const float* __restrict__ bias, const float* __restrict__ res,
    float* __restrict__ outf, unsigned short* __restrict__ outb,
    int M, int K, int N) {
    __shared__ unsigned short As[64][136];
    __shared__ unsigned short Bs[64][136];
    int t = threadIdx.x;
    int wid = t >> 6, lane = t & 63;
    int m0 = blockIdx.y * 64, n0 = blockIdx.x * 64;
    int wm = (wid >> 1) * 32, wn = (wid & 1) * 32;
    f32x4 acc[2][2] = {};
    int srow = t >> 2, sc = (t & 3) * 8;
    const unsigned short* Ap = A + (size_t)(m0 + srow) * K + sc;
    const unsigned short* Bp = Wt + (size_t)(n0 + srow) * K + sc;
    int lr = lane & 15, lk = (lane >> 4) * 8;
    uint4 ra0 = *(const uint4*)(Ap);
    uint4 ra1 = *(const uint4*)(Ap + 32);
    uint4 ra2 = *(const uint4*)(Ap + 64);
    uint4 ra3 = *(const uint4*)(Ap + 96);
    uint4 rb0 = *(const uint4*)(Bp);
    uint4 rb1 = *(const uint4*)(Bp + 32);
    uint4 rb2 = *(const uint4*)(Bp + 64);
    uint4 rb3 = *(const uint4*)(Bp + 96);
    for (int k0 = 0; k0 < K; k0 += 128) {
        *(uint4*)&As[srow][sc]      = ra0;
        *(uint4*)&As[srow][sc + 32] = ra1;
        *(uint4*)&As[srow][sc + 64] = ra2;
        *(uint4*)&As[srow][sc + 96] = ra3;
        *(uint4*)&Bs[srow][sc]      = rb0;
        *(uint4*)&Bs[srow][sc + 32] = rb1;
        *(uint4*)&Bs[srow][sc + 64] = rb2;
        *(uint4*)&Bs[srow][sc + 96] = rb3;
        __syncthreads();
        if (k0 + 128 < K) {
            ra0 = *(const uint4*)(Ap + k0 + 128);
            ra1 = *(const uint4*)(Ap + k0 + 160);
            ra2 = *(const uint4*)(Ap + k0 + 192);
            ra3 = *(const uint4*)(Ap + k0 + 224);
            rb0 = *(const uint4*)(Bp + k0 + 128);
            rb1 = *(const uint4*)(Bp + k0 + 160);
            rb2 = *(const uint4*)(Bp + k0 + 192);
            rb3 = *(const uint4*)(Bp + k0 + 224);
        }
#pragma unroll
        for (int kk = 0; kk < 128; kk += 32) {
            bf16x8 a0 = *(const bf16x8*)&As[wm + lr][kk + lk];
            bf16x8 a1 = *(const bf16x8*)&As[wm + 16 + lr][kk + lk];
            bf16x8 b0 = *(const bf16x8*)&Bs[wn + lr][kk + lk];
            bf16x8 b1 = *(const bf16x8*)&Bs[wn + 16 + lr][kk + lk];
            acc[0][0] = __builtin_amdgcn_mfma_f32_16x16x32_bf16(a0, b0, acc[0][0], 0, 0, 0);
            acc[0][1] = __builtin_amdgcn_mfma_f32_16x16x32_bf16(a0, b1, acc[0][1], 0, 0, 0);
            acc[1][0] = __builtin_amdgcn_mfma_f32_16x16x32_bf16(a1, b0, acc[1][0], 0, 0, 0);
            acc[1][1] = __builtin_amdgcn_mfma_f32_16x16x32_bf16(a1, b1, acc[1][1], 0, 0, 0);
        }
        __syncthreads();
    }
    int lq = lane >> 4;
#pragma unroll
    for (int mi = 0; mi < 2; mi++)
#pragma unroll
        for (int ni = 0; ni < 2; ni++) {
#pragma unroll
            for (int r = 0; r < 4; r++) {
                int grow = m0 + wm + mi * 16 + lq * 4 + r;
                int gcol = n0 + wn + ni * 16 + lr;
                float v = acc[mi][ni][r];
                if (FLAGS & 1) v += bias[gcol];
                if (FLAGS & 2) v = 0.5f * v * (1.f + erff(v * 0.70710678118654752f));
                if (FLAGS & 4) v += res[(size_t)grow * N + gcol];
                if (FLAGS & 8) outb[(size_t)grow * N + gcol] = (unsigned short)f2bf(v);
                else           outf[(size_t)grow * N + gcol] = v;
            }
        }
}

// ---------------------------------------------------------------- bf16 MFMA GEMM 128x128 tile
template <int FLAGS>
__global__ __launch_bounds__(256) void gemm_bf16_128(
    const unsigned short* __restrict__ A, const unsigned short* __restrict__ Wt,
    const float* __restrict__ bias, const float* __restrict__ res,
    float* __restrict__ outf, unsigned short* __restrict__ outb,
    int M, int K, int N) {
    __shared__ unsigned short As[128][72];
    __shared__ unsigned short Bs[128][72];
    int t = threadIdx.x;
    int wid = t >> 6, lane = t & 63;
    int m0 = blockIdx.y * 128, n0 = blockIdx.x * 128;
    int wm = (wid >> 1) * 64, wn = (wid & 1) * 64;
    f32x4 acc[4][4] = {};
    int srow = t >> 3, sc = (t & 7) * 8;    // rows 0..31, 8-col chunks
    const unsigned short* Ap = A + (size_t)(m0 + srow) * K + sc;
    const unsigned short* Bp = Wt + (size_t)(n0 + srow) * K + sc;
    int lr = lane & 15, lk = (lane >> 4) * 8;
    for (int k0 = 0; k0 < K; k0 += 64) {
#pragma unroll
        for (int rr = 0; rr < 4; rr++) {
            *(uint4*)&As[srow + rr * 32][sc] = *(const uint4*)(Ap + (size_t)(rr * 32) * K + k0);
            *(uint4*)&Bs[srow + rr * 32][sc] = *(const uint4*)(Bp + (size_t)(rr * 32) * K + k0);
        }
        __syncthreads();
#pragma unroll
        for (int kk = 0; kk < 64; kk += 32) {
            bf16x8 af[4], bfr[4];
#pragma unroll
            for (int i = 0; i < 4; i++) af[i]  = *(const bf16x8*)&As[wm + i * 16 + lr][kk + lk];
#pragma unroll
            for (int j = 0; j < 4; j++) bfr[j] = *(const bf16x8*)&Bs[wn + j * 16 + lr][kk + lk];
#pragma unroll
            for (int i = 0; i < 4; i++)
#pragma unroll
                for (int j = 0; j < 4; j++)
                    acc[i][j] = __builtin_amdgcn_mfma_f32_16x16x32_bf16(af[i], bfr[j], acc[i][j], 0, 0, 0);
        }
        __syncthreads();
    }
    int lq = lane >> 4;
#pragma unroll
    for (int mi = 0; mi < 4; mi++)
#pragma unroll
        for (int ni = 0; ni < 4; ni++) {
#pragma unroll
            for (int r = 0; r < 4; r++) {
                int grow = m0 + wm + mi * 16 + lq * 4 + r;
                int gcol = n0 + wn + ni * 16 + lr;
                float v = acc[mi][ni][r];
                if (FLAGS & 1) v += bias[gcol];
                if (FLAGS & 2) v = 0.5f * v * (1.f + erff(v * 0.70710678118654752f));
                if (FLAGS & 4) v += res[(size_t)grow * N + gcol];
                if (FLAGS & 8) outb[(size_t)grow * N + gcol] = (unsigned short)f2bf(v);
                else           outf[(size_t)grow * N + gcol] = v;
            }
        }
}

// ---------------------------------------------------------------- qkv GEMM + fused rope (+prefetch)
__global__ __launch_bounds__(256) void gemm_qkv_rope(
    const unsigned short* __restrict__ A, const unsigned short* __restrict__ Wt,
    const float* __restrict__ bias, const float* __restrict__ cosT,
    const float* __restrict__ sinT, unsigned short* __restrict__ qr,
    unsigned short* __restrict__ kr, unsigned short* __restrict__ vt) {
    const int K = 384;
    __shared__ unsigned short As[64][72];
    __shared__ unsigned short Bs[64][72];
    int t = threadIdx.x;
    int wid = t >> 6, lane = t & 63;
    int m0 = blockIdx.y * 64, n0 = blockIdx.x * 64;
    int wm = (wid >> 1) * 32, wn = (wid & 1) * 32;
    f32x4 acc[2][2] = {};
    int srow = t >> 2, sc = (t & 3) * 8;
    const unsigned short* Ap = A + (size_t)(m0 + srow) * K + sc;
    const unsigned short* Bp = Wt + (size_t)(n0 + srow) * K + sc;
    int lr = lane & 15, lk = (lane >> 4) * 8;
    uint4 ra0 = *(const uint4*)(Ap);
    uint4 ra1 = *(const uint4*)(Ap + 32);
    uint4 rb0 = *(const uint4*)(Bp);
    uint4 rb1 = *(const uint4*)(Bp + 32);
    for (int k0 = 0; k0 < K; k0 += 64) {
        *(uint4*)&As[srow][sc]      = ra0;
        *(uint4*)&As[srow][sc + 32] = ra1;
        *(uint4*)&Bs[srow][sc]      = rb0;
        *(uint4*)&Bs[srow][sc + 32] = rb1;
        __syncthreads();
        if (k0 + 64 < K) {
            ra0 = *(const uint4*)(Ap + k0 + 64);
            ra1 = *(const uint4*)(Ap + k0 + 96);
            rb0 = *(const uint4*)(Bp + k0 + 64);
            rb1 = *(const uint4*)(Bp + k0 + 96);
        }
#pragma unroll
        for (int kk = 0; kk < 64; kk += 32) {
            bf16x8 a0 = *(const bf16x8*)&As[wm + lr][kk + lk];
            bf16x8 a1 = *(const bf16x8*)&As[wm + 16 + lr][kk + lk];
            bf16x8 b0 = *(const bf16x8*)&Bs[wn + lr][kk + lk];
            bf16x8 b1 = *(const bf16x8*)&Bs[wn + 16 + lr][kk + lk];
            acc[0][0] = __builtin_amdgcn_mfma_f32_16x16x32_bf16(a0, b0, acc[0][0], 0, 0, 0);
            acc[0][1] = __builtin_amdgcn_mfma_f32_16x16x32_bf16(a0, b1, acc[0][1], 0, 0, 0);
            acc[1][0] = __builtin_amdgcn_mfma_f32_16x16x32_bf16(a1, b0, acc[1][0], 0, 0, 0);
            acc[1][1] = __builtin_amdgcn_mfma_f32_16x16x32_bf16(a1, b1, acc[1][1], 0, 0, 0);
        }
        __syncthreads();
    }
    int lq = lane >> 4;
    int bx = blockIdx.x;
    int sec = bx / 6, hh = bx - sec * 6;
    if (sec == 2) {
#pragma unroll
        for (int mi = 0; mi < 2; mi++)
#pragma unroll
            for (int ni = 0; ni < 2; ni++) {
                int d = wn + ni * 16 + lr;
                float bb = bias[768 + hh * 64 + d];
                int g0 = m0 + wm + mi * 16 + lq * 4;
                int b = g0 >> 10, n = g0 & 1023;
                uint2 u;
                u.x = f2bf(acc[mi][ni][0] + bb) | (f2bf(acc[mi][ni][1] + bb) << 16);
                u.y = f2bf(acc[mi][ni][2] + bb) | (f2bf(acc[mi][ni][3] + bb) << 16);
                *(uint2*)&vt[((size_t)(b * 6 + hh) * HD + d) * NSEQ + n] = u;
            }
    } else {
        unsigned short* dst = sec ? kr : qr;
        float scl = sec ? 1.0f : 0.125f;
#pragma unroll
        for (int mi = 0; mi < 2; mi++)
#pragma unroll
            for (int ni = 0; ni < 2; ni++) {
                int d = wn + ni * 16 + lr;
                float bb = bias[sec * 384 + hh * 64 + d];
                int pp = d >> 1;
#pragma unroll
                for (int r = 0; r < 4; r++) {
                    int grow = m0 + wm + mi * 16 + lq * 4 + r;
                    float v = acc[mi][ni][r] + bb;
                    float c = cosT[(size_t)grow * 32 + pp];
                    float s = sinT[(size_t)grow * 32 + pp];
                    float vp = __shfl_xor(v, 1);
                    float out = ((d & 1) == 0 ? v * c - vp * s : vp * s + v * c) * scl;
                    int b = grow >> 10, n = grow & 1023;
                    dst[((size_t)(b * 6 + hh) * NSEQ + n) * HD + d] = (unsigned short)f2bf(out);
                }
            }
    }
}

// ---------------------------------------------------------------- split-K(4) attn, Q-tile 128
__global__ __launch_bounds__(256) void attn_mfma(
    const unsigned short* __restrict__ qr, const unsigned short* __restrict__ kr,
    const unsigned short* __restrict__ vt, unsigned short* __restrict__ opart,
    float* __restrict__ mP, float* __restrict__ lP) {
    __shared__ unsigned short Ks[64][72];        // [key][d]
    __shared__ unsigned short Vs[64][72];        // [d][key]
    __shared__ unsigned short Pb[2][4][16][72];  // per-half, per-wave P [q][k]
    __shared__ float Aw[2][4][16];               // per-half alpha/l broadcast
    int bh = blockIdx.x;
    int q0 = blockIdx.y * 128;
    int z  = blockIdx.z;
    int len = c_lens[bh / 6];
    int T = len >> 6;
    int t0 = (T * z) >> 2, t1 = (T * (z + 1)) >> 2;   // NZ=4 quarters
    int t = threadIdx.x, wid = t >> 6, lane = t & 63;
    int lz = lane & 15, lq = lane >> 4;
    bf16x8 qa0[2], qa1[2];
#pragma unroll
    for (int h = 0; h < 2; h++) {
        const unsigned short* Qp =
            qr + ((size_t)bh * NSEQ + q0 + h * 64 + wid * 16 + lz) * HD + lq * 8;
        qa0[h] = *(const bf16x8*)(Qp);
        qa1[h] = *(const bf16x8*)(Qp + 32);
    }
    int srow = t >> 2, sc = (t & 3) * 16;      // K: row=key, V: row=d
    const unsigned short* Kp = kr + (size_t)bh * NSEQ * HD + (size_t)srow * HD + sc;
    const unsigned short* Vp = vt + ((size_t)bh * HD + srow) * NSEQ + sc;
    f32x4 oacc[2][4] = {};
    float m_s[2] = {-1e30f, -1e30f}, l_s[2] = {0.f, 0.f};
    uint4 rk0, rk1, rv0, rv1;
    {
        int k0 = t0 << 6;
        rk0 = *(const uint4*)(Kp + (size_t)k0 * HD);
        rk1 = *(const uint4*)(Kp + (size_t)k0 * HD + 8);
        rv0 = *(const uint4*)(Vp + k0);
        rv1 = *(const uint4*)(Vp + k0 + 8);
    }
    for (int kt = t0; kt < t1; kt++) {
        *(uint4*)&Ks[srow][sc]     = rk0;
        *(uint4*)&Ks[srow][sc + 8] = rk1;
        *(uint4*)&Vs[srow][sc]     = rv0;
        *(uint4*)&Vs[srow][sc + 8] = rv1;
        __syncthreads();
        uint4 nk0, nk1, nv0, nv1;
        if (kt + 1 < t1) {
            int k1 = (kt + 1) << 6;
            nk0 = *(const uint4*)(Kp + (size_t)k1 * HD);
            nk1 = *(const uint4*)(Kp + (size_t)k1 * HD + 8);
            nv0 = *(const uint4*)(Vp + k1);
            nv1 = *(const uint4*)(Vp + k1 + 8);
        }
#pragma unroll
        for (int h = 0; h < 2; h++) {
            f32x4 s[4] = {};
            __builtin_amdgcn_s_setprio(1);
#pragma unroll
            for (int g = 0; g < 4; g++) {
                bf16x8 kf0 = *(const bf16x8*)&Ks[g * 16 + lz][lq * 8];
                bf16x8 kf1 = *(const bf16x8*)&Ks[g * 16 + lz][32 + lq * 8];
                s[g] = __builtin_amdgcn_mfma_f32_16x16x32_bf16(kf0, qa0[h], s[g], 0, 0, 0);
                s[g] = __builtin_amdgcn_mfma_f32_16x16x32_bf16(kf1, qa1[h], s[g], 0, 0, 0);
            }
            __builtin_amdgcn_s_setprio(0);
            float mx = s[0][0];
#pragma unroll
            for (int g = 0; g < 4; g++)
#pragma unroll
                for (int r = 0; r < 4; r++) mx = fmaxf(mx, s[g][r]);
            mx = fmaxf(mx, __shfl_xor(mx, 16));
            mx = fmaxf(mx, __shfl_xor(mx, 32));
            float mn = fmaxf(m_s[h], mx);
            float a_s = __expf(m_s[h] - mn);
            m_s[h] = mn;
            float sum = 0.f;
#pragma unroll
            for (int g = 0; g < 4; g++)
#pragma unroll
                for (int r = 0; r < 4; r++) {
                    float p = __expf(s[g][r] - mn);
                    s[g][r] = p;
                    sum += p;
                }
            sum += __shfl_xor(sum, 16);
            sum += __shfl_xor(sum, 32);
            l_s[h] = l_s[h] * a_s + sum;
            if (lq == 0) Aw[h][wid][lz] = a_s;
#pragma unroll
            for (int g = 0; g < 4; g++) {
                uint2 u;
                u.x = f2bf(s[g][0]) | (f2bf(s[g][1]) << 16);
                u.y = f2bf(s[g][2]) | (f2bf(s[g][3]) << 16);
                *(uint2*)&Pb[h][wid][lz][g * 16 + lq * 4] = u;
            }
            f32x4 al4 = *(const f32x4*)&Aw[h][wid][lq * 4];
            bf16x8 pa0 = *(const bf16x8*)&Pb[h][wid][lz][lq * 8];
            bf16x8 pa1 = *(const bf16x8*)&Pb[h][wid][lz][32 + lq * 8];
            __builtin_amdgcn_s_setprio(1);
#pragma unroll
            for (int g = 0; g < 4; g++) {
#pragma unroll
                for (int r = 0; r < 4; r++) oacc[h][g][r] *= al4[r];
                bf16x8 vf0 = *(const bf16x8*)&Vs[g * 16 + lz][lq * 8];
                bf16x8 vf1 = *(const bf16x8*)&Vs[g * 16 + lz][32 + lq * 8];
                oacc[h][g] = __builtin_amdgcn_mfma_f32_16x16x32_bf16(pa0, vf0, oacc[h][g], 0, 0, 0);
                oacc[h][g] = __builtin_amdgcn_mfma_f32_16x16x32_bf16(pa1, vf1, oacc[h][g], 0, 0, 0);
            }
            __builtin_amdgcn_s_setprio(0);
        }
        __syncthreads();   // all waves done reading before next ds_write
        rk0 = nk0; rk1 = nk1; rv0 = nv0; rv1 = nv1;
    }
#pragma unroll
    for (int h = 0; h < 2; h++) {
        size_t rb = ((size_t)z * 24 + bh) * NSEQ + q0 + h * 64 + wid * 16;
        if (lq == 0) { mP[rb + lz] = m_s[h]; lP[rb + lz] = l_s[h]; }
#pragma unroll
        for (int r = 0; r < 4; r++) {
            int row = lq * 4 + r;
#pragma unroll
            for (int g = 0; g < 4; g++)
                opart[(rb + row) * HD + g * 16 + lz] = (unsigned short)f2bf(oacc[h][g][r]);
        }
    }
}

// ---------------------------------------------------------------- proj GEMM + fused 4-way combine
__global__ __launch_bounds__(256) void gemm_proj_combine(
    const unsigned short* __restrict__ opart, const float* __restrict__ mP,
    const float* __restrict__ lP, const unsigned short* __restrict__ Wt,
    const float* __restrict__ bias, float* __restrict__ xio) {
    const int K = 384, N = 384;
    __shared__ unsigned short As[64][72];
    __shared__ unsigned short Bs[64][72];
    __shared__ float Winv[64][6][NZ];          // 6 KB
    int t = threadIdx.x;
    int wid = t >> 6, lane = t & 63;
    int m0 = blockIdx.y * 64, n0 = blockIdx.x * 64;
    int wm = (wid >> 1) * 32, wn = (wid & 1) * 32;
    const size_t zstride = (size_t)24 * NSEQ * HD;
    for (int p = t; p < 384; p += 256) {
        int tok = p / 6, hh = p - tok * 6;
        int g = m0 + tok, b = g >> 10, n = g & 1023;
        int bh = b * 6 + hh;
        size_t i0 = (size_t)bh * NSEQ + n;
        float m[NZ], l[NZ], w[NZ];
        float ms = -1e30f;
#pragma unroll
        for (int z = 0; z < NZ; z++) {
            m[z] = mP[i0 + (size_t)z * 24 * NSEQ];
            l[z] = lP[i0 + (size_t)z * 24 * NSEQ];
            ms = fmaxf(ms, m[z]);
        }
        float ls = 0.f;
#pragma unroll
        for (int z = 0; z < NZ; z++) { w[z] = __expf(m[z] - ms); ls += l[z] * w[z]; }
        float inv = 1.f / ls;
#pragma unroll
        for (int z = 0; z < NZ; z++) Winv[tok][hh][z] = w[z] * inv;
    }
    __syncthreads();
    f32x4 acc[2][2] = {};
    int srow = t >> 2, sc = (t & 3) * 8;
    int gg = m0 + srow, gb = gg >> 10, gn = gg & 1023;
    const unsigned short* Bp = Wt + (size_t)(n0 + srow) * K + sc;
    int lr = lane & 15, lk = (lane >> 4) * 8;
    for (int k0 = 0; k0 < K; k0 += 64) {
#pragma unroll
        for (int h = 0; h < 2; h++) {
            int col = k0 + sc + h * 32;
            int hh = col >> 6, d = col & 63;
            int bh = gb * 6 + hh;
            size_t base = ((size_t)bh * NSEQ + gn) * HD + d;
            float wz[NZ];
#pragma unroll
            for (int z = 0; z < NZ; z++) wz[z] = Winv[srow][hh][z];
            float lo[4] = {0.f, 0.f, 0.f, 0.f}, hi[4] = {0.f, 0.f, 0.f, 0.f};
#pragma unroll
            for (int z = 0; z < NZ; z++) {
                uint4 u = *(const uint4*)&opart[base + (size_t)z * zstride];
                unsigned a[4] = {u.x, u.y, u.z, u.w};
#pragma unroll
                for (int q = 0; q < 4; q++) {
                    lo[q] += bf2f((unsigned short)(a[q] & 0xffff)) * wz[z];
                    hi[q] += bf2f((unsigned short)(a[q] >> 16)) * wz[z];
                }
            }
            uint4 outw;
            unsigned rr[4];
#pragma unroll
            for (int q = 0; q < 4; q++) rr[q] = f2bf(lo[q]) | (f2bf(hi[q]) << 16);
            outw.x = rr[0]; outw.y = rr[1]; outw.z = rr[2]; outw.w = rr[3];
            *(uint4*)&As[srow][sc + h * 32] = outw;
        }
        *(uint4*)&Bs[srow][sc]      = *(const uint4*)(Bp + k0);
        *(uint4*)&Bs[srow][sc + 32] = *(const uint4*)(Bp + k0 + 32);
        __syncthreads();
#pragma unroll
        for (int kk = 0; kk < 64; kk += 32) {
            bf16x8 a0 = *(const bf16x8*)&As[wm + lr][kk + lk];
            bf16x8 a1 = *(const bf16x8*)&As[wm + 16 + lr][kk + lk];
            bf16x8 b0 = *(const bf16x8*)&Bs[wn + lr][kk + lk];
            bf16x8 b1 = *(const bf16x8*)&Bs[wn + 16 + lr][kk + lk];
            acc[0][0] = __builtin_amdgcn_mfma_f32_16x16x32_bf16(a0, b0, acc[0][0], 0, 0, 0);
            acc[0][1] = __builtin_amdgcn_mfma_f32_16x16x32_bf16(a0, b1, acc[0][1], 0, 0, 0);
            acc[1][0] = __builtin_amdgcn_mfma_f32_16x16x32_bf16(a1, b0, acc[1][0], 0, 0, 0);
            acc[1][1] = __builtin_amdgcn_mfma_f32_16x16x32_bf16(a1, b1, acc[1][1], 0, 0, 0);
        }
        __syncthreads();
    }
    int lq = lane >> 4;
#pragma unroll
    for (int mi = 0; mi < 2; mi++)
#pragma unroll
        for (int ni = 0; ni < 2; ni++) {
#pragma unroll
            for (int r = 0; r < 4; r++) {
                int grow = m0 + wm + mi * 16 + lq * 4 + r;
                int gcol = n0 + wn + ni * 16 + lr;
                float v = acc[mi][ni][r] + bias[gcol] + xio[(size_t)grow * N + gcol];
                xio[(size_t)grow * N + gcol] = v;
            }
        }
}

// ---------------------------------------------------------------- launch
extern "C" void kernel_launch(void* const* d_in, const int* in_sizes, int n_in,
                              void* d_out, int out_size, void* d_ws, size_t ws_size,
                              hipStream_t stream) {
    (void)in_sizes; (void)n_in; (void)out_size; (void)ws_size;
    const float* img0 = (const float*)d_in[0];
    const float* img1 = (const float*)d_in[1];
    const float* img2 = (const float*)d_in[2];
    const float* img3 = (const float*)d_in[3];
    const float* pe_ln_in_w  = (const float*)d_in[4];
    const float* pe_ln_in_b  = (const float*)d_in[5];
    const float* pe_w        = (const float*)d_in[6];
    const float* pe_ln_out_w = (const float*)d_in[7];
    const float* pe_ln_out_b = (const float*)d_in[8];
    const float* ln1_w  = (const float*)d_in[9];
    const float* ln1_b  = (const float*)d_in[10];
    const float* qkv_w  = (const float*)d_in[11];
    const float* qkv_b  = (const float*)d_in[12];
    const float* proj_w = (const float*)d_in[13];
    const float* proj_b = (const float*)d_in[14];
    const float* ln2_w  = (const float*)d_in[15];
    const float* ln2_b  = (const float*)d_in[16];
    const float* fc1_w  = (const float*)d_in[17];
    const float* fc1_b  = (const float*)d_in[18];
    const float* fc2_w  = (const float*)d_in[19];
    const float* fc2_b  = (const float*)d_in[20];
    const float* lnf_w  = (const float*)d_in[21];
    const float* lnf_b  = (const float*)d_in[22];

    char* ws = (char*)d_ws;
    float*          x_f    = (float*)(ws + 0);                    //  6,291,456
    char*           R      = ws + 6291456;                        // 12,582,912 union region
    unsigned short* opart  = (unsigned short*)R;                  // 12,582,912 (attn partials, NZ=4)
    unsigned short* mlp_bf = (unsigned short*)R;                  // 12,582,912 (MLP phase only)
    unsigned short* h_bf   = (unsigned short*)(ws + 18874368);    //  3,145,728 (ln1/ln2 out)
    unsigned short* qr     = (unsigned short*)(ws + 22020096);    //  3,145,728
    unsigned short* kr     = (unsigned short*)(ws + 25165824);    //  3,145,728
    unsigned short* vt     = (unsigned short*)(ws + 28311552);    //  3,145,728
    float*          cosT   = (float*)(ws + 31457280);             //    524,288
    float*          sinT   = (float*)(ws + 31981568);             //    524,288
    float*          xin    = (float*)(ws + 32505856);             //  1,572,864 (dead after embed)
    float*          mPt    = xin;                                 //    393,216 (attn m partials, NZ=4)
    float*          lPt    = (float*)(ws + 32505856 + 393216);    //    393,216 (attn l partials)
    unsigned short* xln_bf = (unsigned short*)(ws + 34078720);    //  1,048,576
    unsigned short* pe_wt  = (unsigned short*)(ws + 35127296);    //     98,304
    unsigned short* qkv_wt = (unsigned short*)(ws + 35225600);    // 10,616,832
    unsigned short* proj_wt= (unsigned short*)(ws + 45842432);    //  3,538,944
    unsigned short* fc1_wt = (unsigned short*)(ws + 49381376);    // 14,155,776
    unsigned short* fc2_wt = (unsigned short*)(ws + 63537152);    // 14,155,776
    // total ~77.7 MB

    // fused prologue: patchify + all 5 weight conversions, one dispatch
    prologue_kernel<<<24880, 256, 0, stream>>>(
        img0, img1, img2, img3, xin, cosT, sinT,
        pe_w, pe_wt, qkv_w, qkv_wt, proj_w, proj_wt, fc1_w, fc1_wt, fc2_w, fc2_wt);

    ln_kernel<PD, 128, true><<<NROWS / 4, 256, 0, stream>>>(xin, pe_ln_in_w, pe_ln_in_b, xln_bf);
    gemm_bf16<0><<<dim3(EMBED / 64, NROWS / 64), 256, 0, stream>>>(
        xln_bf, pe_wt, nullptr, nullptr, x_f, nullptr, NROWS, 128, EMBED);
    ln_kernel<EMBED, EMBED, false><<<NROWS / 4, 256, 0, stream>>>(x_f, pe_ln_out_w, pe_ln_out_b, x_f);

    for (int l = 0; l < 12; ++l) {
        ln_kernel<EMBED, EMBED, true><<<NROWS / 4, 256, 0, stream>>>(
            x_f, ln1_w + l * EMBED, ln1_b + l * EMBED, h_bf);
        gemm_qkv_rope<<<dim3(18, NROWS / 64), 256, 0, stream>>>(
            h_bf, qkv_wt + (size_t)l * 1152 * 384, qkv_b + (size_t)l * 1152,
            cosT, sinT, qr, kr, vt);
        attn_mfma<<<dim3(NB * NHEADS, NSEQ / 128, NZ), 256, 0, stream>>>(
            qr, kr, vt, opart, mPt, lPt);
        gemm_proj_combine<<<dim3(EMBED / 64, NROWS / 64), 256, 0, stream>>>(
            opart, mPt, lPt, proj_wt + (size_t)l * 384 * 384,
            proj_b + (size_t)l * EMBED, x_f);
        ln_kernel<EMBED, EMBED, true><<<NROWS / 4, 256, 0, stream>>>(
            x_f, ln2_w + l * EMBED, ln2_b + l * EMBED, h_bf);
        gemm_bf16_128<11><<<dim3(1536 / 128, NROWS / 128), 256, 0, stream>>>(
            h_bf, fc1_wt + (size_t)l * 1536 * 384, fc1_b + (size_t)l * 1536, nullptr,
            nullptr, mlp_bf, NROWS, EMBED, 1536);
        gemm_bf16_bk128<5><<<dim3(EMBED / 64, NROWS / 64), 256, 0, stream>>>(
            mlp_bf, fc2_wt + (size_t)l * 1536 * 384, fc2_b + (size_t)l * EMBED, x_f,
            x_f, nullptr, NROWS, 1536, EMBED);
    }

    ln_kernel<EMBED, EMBED, false, true><<<NROWS / 4, 256, 0, stream>>>(
        x_f, lnf_w, lnf_b, (float*)d_out);
}